// Round 2
// baseline (16420.067 us; speedup 1.0000x reference)
//
#include <hip/hip_runtime.h>

#define N_NODES 50000
#define N_EDGES 800000
#define N_GRAPHS 512
#define IN_DIM 256
#define HID 512
#define BN_EPS 1e-5f

// ---------------------------------------------------------------- copy (f4)
__global__ __launch_bounds__(256) void copy_f4(const float4* __restrict__ s,
                                               float4* __restrict__ d, int n4) {
  for (int i = blockIdx.x * 256 + threadIdx.x; i < n4; i += gridDim.x * 256)
    d[i] = s[i];
}

// ------------------------------------------------- edge scatter-add: z[dst] += h[src]
__global__ __launch_bounds__(256) void edge_agg(const int* __restrict__ src,
                                                const int* __restrict__ dst,
                                                const float* __restrict__ h,
                                                float* __restrict__ z,
                                                int lgDq, int D) {
  const int Dq = 1 << lgDq;
  const long long total = (long long)N_EDGES << lgDq;
  for (long long i = (long long)blockIdx.x * 256 + threadIdx.x; i < total;
       i += (long long)gridDim.x * 256) {
    int e = (int)(i >> lgDq);
    int c = (int)(i & (Dq - 1));
    int s = src[e];
    int d = dst[e];
    float4 v = ((const float4*)(h + (long long)s * D))[c];
    float* zp = z + (long long)d * D + c * 4;
    atomicAdd(zp + 0, v.x);
    atomicAdd(zp + 1, v.y);
    atomicAdd(zp + 2, v.z);
    atomicAdd(zp + 3, v.w);
  }
}

// ------------------------------------------------- fp32 GEMM: C = act(A[NxK] @ W[KxM] + bias), M=512
__global__ __launch_bounds__(256) void gemm_bias_act(const float* __restrict__ A,
                                                     const float* __restrict__ W,
                                                     const float* __restrict__ bias,
                                                     float* __restrict__ C,
                                                     int N, int K, int relu) {
  const int M = HID;
  __shared__ float As[16][68];
  __shared__ float Ws[16][68];
  const int tid = threadIdx.x;
  const int tx = tid & 15, ty = tid >> 4;
  const int row0 = blockIdx.y * 64, col0 = blockIdx.x * 64;
  const int la_n = tid >> 2, la_k = (tid & 3) << 2;
  const int lw_k = tid >> 4, lw_m = (tid & 15) << 2;

  float acc[4][4] = {};

  for (int k0 = 0; k0 < K; k0 += 16) {
    int arow = row0 + la_n;
    float4 av = make_float4(0.f, 0.f, 0.f, 0.f);
    if (arow < N) av = *(const float4*)(A + (long long)arow * K + (k0 + la_k));
    As[la_k + 0][la_n] = av.x;
    As[la_k + 1][la_n] = av.y;
    As[la_k + 2][la_n] = av.z;
    As[la_k + 3][la_n] = av.w;
    float4 wv = *(const float4*)(W + (long long)(k0 + lw_k) * M + (col0 + lw_m));
    *(float4*)&Ws[lw_k][lw_m] = wv;
    __syncthreads();
#pragma unroll
    for (int k = 0; k < 16; ++k) {
      float4 a = *(const float4*)&As[k][ty << 2];
      float4 b = *(const float4*)&Ws[k][tx << 2];
      acc[0][0] += a.x * b.x; acc[0][1] += a.x * b.y; acc[0][2] += a.x * b.z; acc[0][3] += a.x * b.w;
      acc[1][0] += a.y * b.x; acc[1][1] += a.y * b.y; acc[1][2] += a.y * b.z; acc[1][3] += a.y * b.w;
      acc[2][0] += a.z * b.x; acc[2][1] += a.z * b.y; acc[2][2] += a.z * b.z; acc[2][3] += a.z * b.w;
      acc[3][0] += a.w * b.x; acc[3][1] += a.w * b.y; acc[3][2] += a.w * b.z; acc[3][3] += a.w * b.w;
    }
    __syncthreads();
  }

  const int cbase = col0 + (tx << 2);
  float4 bv = *(const float4*)(bias + cbase);
#pragma unroll
  for (int i = 0; i < 4; ++i) {
    int r = row0 + (ty << 2) + i;
    if (r >= N) break;
    float4 o;
    o.x = acc[i][0] + bv.x;
    o.y = acc[i][1] + bv.y;
    o.z = acc[i][2] + bv.z;
    o.w = acc[i][3] + bv.w;
    if (relu) {
      o.x = fmaxf(o.x, 0.f); o.y = fmaxf(o.y, 0.f);
      o.z = fmaxf(o.z, 0.f); o.w = fmaxf(o.w, 0.f);
    }
    *(float4*)(C + (long long)r * M + cbase) = o;
  }
}

// ------------------------------------------------- BN statistics (sum, sumsq per channel)
__global__ __launch_bounds__(256) void bn_stats(const float* __restrict__ z,
                                                float* __restrict__ sum,
                                                float* __restrict__ sumsq) {
  const int tid = threadIdx.x;
  const int c0 = tid, c1 = tid + 256;
  float s0 = 0.f, q0 = 0.f, s1 = 0.f, q1 = 0.f;
  for (int n = blockIdx.x; n < N_NODES; n += gridDim.x) {
    float v0 = z[(long long)n * HID + c0];
    float v1 = z[(long long)n * HID + c1];
    s0 += v0; q0 += v0 * v0;
    s1 += v1; q1 += v1 * v1;
  }
  atomicAdd(&sum[c0], s0);
  atomicAdd(&sumsq[c0], q0);
  atomicAdd(&sum[c1], s1);
  atomicAdd(&sumsq[c1], q1);
}

// ------------------------------------------------- BN apply + affine + relu
__global__ __launch_bounds__(256) void bn_apply(const float4* __restrict__ z,
                                                const float* __restrict__ sum,
                                                const float* __restrict__ sumsq,
                                                const float4* __restrict__ g4,
                                                const float4* __restrict__ b4,
                                                float4* __restrict__ h) {
  const float invN = 1.0f / (float)N_NODES;
  const int total4 = N_NODES * (HID / 4);
  for (int i = blockIdx.x * 256 + threadIdx.x; i < total4; i += gridDim.x * 256) {
    int c = i & 127;
    float4 s = ((const float4*)sum)[c];
    float4 q = ((const float4*)sumsq)[c];
    float4 gg = g4[c];
    float4 bb = b4[c];
    float4 zv = z[i];
    float4 o;
    float mu, var, sc;
    mu = s.x * invN; var = q.x * invN - mu * mu; sc = rsqrtf(var + BN_EPS) * gg.x;
    o.x = fmaxf((zv.x - mu) * sc + bb.x, 0.f);
    mu = s.y * invN; var = q.y * invN - mu * mu; sc = rsqrtf(var + BN_EPS) * gg.y;
    o.y = fmaxf((zv.y - mu) * sc + bb.y, 0.f);
    mu = s.z * invN; var = q.z * invN - mu * mu; sc = rsqrtf(var + BN_EPS) * gg.z;
    o.z = fmaxf((zv.z - mu) * sc + bb.z, 0.f);
    mu = s.w * invN; var = q.w * invN - mu * mu; sc = rsqrtf(var + BN_EPS) * gg.w;
    o.w = fmaxf((zv.w - mu) * sc + bb.w, 0.f);
    h[i] = o;
  }
}

// ------------------------------------------------- global add pool (atomic scatter)
__global__ __launch_bounds__(256) void gpool_kernel(const float* __restrict__ h,
                                                    const int* __restrict__ batch,
                                                    float* __restrict__ gp) {
  const int total = N_NODES * (HID / 4);
  for (int i = blockIdx.x * 256 + threadIdx.x; i < total; i += gridDim.x * 256) {
    int n = i >> 7;
    int c = i & 127;
    int g = batch[n];
    float4 v = ((const float4*)(h + (long long)n * HID))[c];
    float* p = gp + (long long)g * HID + c * 4;
    atomicAdd(p + 0, v.x);
    atomicAdd(p + 1, v.y);
    atomicAdd(p + 2, v.z);
    atomicAdd(p + 3, v.w);
  }
}

// ------------------------------------------------- classifier tail: GEMV(512x10) + softmax + argmax + one_hot
__global__ __launch_bounds__(64) void clf2_softmax(const float* __restrict__ hidden,
                                                   const float* __restrict__ w2,
                                                   const float* __restrict__ b2,
                                                   float* __restrict__ out) {
  const int g = blockIdx.x;      // 512 graphs
  const int lane = threadIdx.x;  // 64
  float acc[10];
#pragma unroll
  for (int j = 0; j < 10; ++j) acc[j] = 0.f;
  for (int k = lane; k < HID; k += 64) {
    float hv = hidden[(long long)g * HID + k];
#pragma unroll
    for (int j = 0; j < 10; ++j) acc[j] += hv * w2[k * 10 + j];
  }
#pragma unroll
  for (int j = 0; j < 10; ++j) {
    for (int off = 32; off > 0; off >>= 1) acc[j] += __shfl_down(acc[j], off);
  }
  if (lane == 0) {
    float lg[10], pb[10];
    float mx = -1e30f;
#pragma unroll
    for (int j = 0; j < 10; ++j) {
      lg[j] = acc[j] + b2[j];
      mx = fmaxf(mx, lg[j]);
    }
    float se = 0.f;
#pragma unroll
    for (int j = 0; j < 10; ++j) {
      pb[j] = __expf(lg[j] - mx);
      se += pb[j];
    }
    float inv = 1.f / se;
    int am = 0;
    float best = lg[0];
#pragma unroll
    for (int j = 1; j < 10; ++j) {
      if (lg[j] > best) { best = lg[j]; am = j; }
    }
#pragma unroll
    for (int j = 0; j < 10; ++j) out[g * 10 + j] = lg[j];
#pragma unroll
    for (int j = 0; j < 10; ++j) out[N_GRAPHS * 10 + g * 10 + j] = pb[j] * inv;
    out[2 * N_GRAPHS * 10 + g] = (float)am;
#pragma unroll
    for (int j = 0; j < 10; ++j)
      out[2 * N_GRAPHS * 10 + N_GRAPHS + g * 10 + j] = (j == am) ? 1.f : 0.f;
  }
}

// ----------------------------------------------------------------- launch
extern "C" void kernel_launch(void* const* d_in, const int* in_sizes, int n_in,
                              void* d_out, int out_size, void* d_ws, size_t ws_size,
                              hipStream_t stream) {
  const float* x = (const float*)d_in[0];
  const int* src = (const int*)d_in[1];
  const int* dstE = src + N_EDGES;
  const int* batch = (const int*)d_in[2];
  const float* w0a = (const float*)d_in[3];
  const float* b0a = (const float*)d_in[4];
  const float* w0b = (const float*)d_in[5];
  const float* b0b = (const float*)d_in[6];
  const float* w1a = (const float*)d_in[7];
  const float* b1a = (const float*)d_in[8];
  const float* w1b = (const float*)d_in[9];
  const float* b1b = (const float*)d_in[10];
  const float* w2a = (const float*)d_in[11];
  const float* b2a = (const float*)d_in[12];
  const float* w2b = (const float*)d_in[13];
  const float* b2b = (const float*)d_in[14];
  const float* bng[3] = {(const float*)d_in[15], (const float*)d_in[17], (const float*)d_in[19]};
  const float* bnb[3] = {(const float*)d_in[16], (const float*)d_in[18], (const float*)d_in[20]};
  const float* clf_w1 = (const float*)d_in[21];
  const float* clf_b1 = (const float*)d_in[22];
  const float* clf_w2 = (const float*)d_in[23];
  const float* clf_b2 = (const float*)d_in[24];
  float* out = (float*)d_out;

  // Workspace layout — only TWO [N_NODES x HID] fp32 buffers (~207 MB total).
  float* bufA = (float*)d_ws;                        // z / z2
  float* bufB = bufA + (long long)N_NODES * HID;     // z1 / h'
  float* bnsum = bufB + (long long)N_NODES * HID;    // 512
  float* bnsq = bnsum + HID;                         // 512
  float* gp = bnsq + HID;                            // 512*512
  float* hidden = gp + (long long)N_GRAPHS * HID;    // 512*512

  const float* wa[3] = {w0a, w1a, w2a};
  const float* ba[3] = {b0a, b1a, b2a};
  const float* wb[3] = {w0b, w1b, w2b};
  const float* bb[3] = {b0b, b1b, b2b};

  const float* h = x;
  int D = IN_DIM;
  for (int layer = 0; layer < 3; ++layer) {
    int n4 = N_NODES * D / 4;
    // z = h (copy), then z[dst] += h[src]   (h is x or bufB; writes go to bufA)
    hipLaunchKernelGGL(copy_f4, dim3(2048), dim3(256), 0, stream,
                       (const float4*)h, (float4*)bufA, n4);
    hipLaunchKernelGGL(edge_agg, dim3(4096), dim3(256), 0, stream,
                       src, dstE, h, bufA, (D == 256) ? 6 : 7, D);
    // z1 = relu(z @ wa + ba)   (h in bufB is dead now)
    hipLaunchKernelGGL(gemm_bias_act, dim3(8, (N_NODES + 63) / 64), dim3(256), 0, stream,
                       bufA, wa[layer], ba[layer], bufB, N_NODES, D, 1);
    // z2 = z1 @ wb + bb        (z in bufA is dead now)
    hipLaunchKernelGGL(gemm_bias_act, dim3(8, (N_NODES + 63) / 64), dim3(256), 0, stream,
                       bufB, wb[layer], bb[layer], bufA, N_NODES, HID, 0);
    // batchnorm: stats over bufA, apply -> bufB
    hipMemsetAsync(bnsum, 0, 2 * HID * sizeof(float), stream);
    hipLaunchKernelGGL(bn_stats, dim3(512), dim3(256), 0, stream, bufA, bnsum, bnsq);
    hipLaunchKernelGGL(bn_apply, dim3(4096), dim3(256), 0, stream,
                       (const float4*)bufA, bnsum, bnsq,
                       (const float4*)bng[layer], (const float4*)bnb[layer], (float4*)bufB);
    h = bufB;
    D = HID;
  }

  // global add pool
  hipMemsetAsync(gp, 0, (size_t)N_GRAPHS * HID * sizeof(float), stream);
  hipLaunchKernelGGL(gpool_kernel, dim3(2048), dim3(256), 0, stream, bufB, batch, gp);
  // classifier layer 1
  hipLaunchKernelGGL(gemm_bias_act, dim3(8, 8), dim3(256), 0, stream,
                     gp, clf_w1, clf_b1, hidden, N_GRAPHS, HID, 1);
  // classifier layer 2 + softmax + argmax + one_hot
  hipLaunchKernelGGL(clf2_softmax, dim3(N_GRAPHS), dim3(64), 0, stream,
                     hidden, clf_w2, clf_b2, out);
}

// Round 3
// 3643.809 us; speedup vs baseline: 4.5063x; 4.5063x over previous
//
#include <hip/hip_runtime.h>

#define N_NODES 50000
#define N_EDGES 800000
#define N_GRAPHS 512
#define IN_DIM 256
#define HID 512
#define BN_EPS 1e-5f

// ------------------------------------------------- CSR build: histogram of dst
__global__ __launch_bounds__(256) void hist_dst(const int* __restrict__ dst,
                                                int* __restrict__ deg) {
  for (int e = blockIdx.x * 256 + threadIdx.x; e < N_EDGES; e += gridDim.x * 256)
    atomicAdd(&deg[dst[e]], 1);
}

// ------------------------------------------------- CSR build: exclusive scan (single block)
__global__ __launch_bounds__(1024) void scan_deg(const int* __restrict__ deg,
                                                 int* __restrict__ off,
                                                 int* __restrict__ cursor) {
  __shared__ int partial[1024];
  const int t = threadIdx.x;
  const int CHUNK = 49;  // 1024*49 = 50176 >= 50000
  const int base = t * CHUNK;
  int mysum = 0;
#pragma unroll 4
  for (int i = 0; i < CHUNK; ++i) {
    int idx = base + i;
    if (idx < N_NODES) mysum += deg[idx];
  }
  partial[t] = mysum;
  __syncthreads();
  // Hillis-Steele inclusive scan over 1024
  for (int st = 1; st < 1024; st <<= 1) {
    int v = (t >= st) ? partial[t - st] : 0;
    __syncthreads();
    partial[t] += v;
    __syncthreads();
  }
  int run = partial[t] - mysum;  // exclusive prefix for this chunk
  for (int i = 0; i < CHUNK; ++i) {
    int idx = base + i;
    if (idx < N_NODES) {
      off[idx] = run;
      cursor[idx] = run;
      run += deg[idx];
    }
  }
  if (t == 1023) off[N_NODES] = N_EDGES;
}

// ------------------------------------------------- CSR build: fill edge lists
__global__ __launch_bounds__(256) void fill_csr(const int* __restrict__ src,
                                                const int* __restrict__ dst,
                                                int* __restrict__ cursor,
                                                int* __restrict__ eidx) {
  for (int e = blockIdx.x * 256 + threadIdx.x; e < N_EDGES; e += gridDim.x * 256) {
    int p = atomicAdd(&cursor[dst[e]], 1);
    eidx[p] = src[e];
  }
}

// ------------------------------------------------- gather-aggregate: z[n] = h[n] + sum_{s in N(n)} h[s]
// one wave per node; ROWF4 = (D/4)/64 float4 regs per lane (1 for D=256, 2 for D=512)
template <int ROWF4>
__global__ __launch_bounds__(256) void agg_csr(const float4* __restrict__ h4,
                                               const int* __restrict__ off,
                                               const int* __restrict__ eidx,
                                               float4* __restrict__ z4) {
  const int n = blockIdx.x * 4 + (threadIdx.x >> 6);
  if (n >= N_NODES) return;
  const int lane = threadIdx.x & 63;
  const int ROW = ROWF4 * 64;  // float4s per row
  float4 v[ROWF4];
  const float4* hn = h4 + (long long)n * ROW;
#pragma unroll
  for (int j = 0; j < ROWF4; ++j) v[j] = hn[j * 64 + lane];

  int p = off[n];
  const int pe = off[n + 1];
  for (; p + 2 <= pe; p += 2) {
    int s0 = eidx[p], s1 = eidx[p + 1];
    const float4* h0 = h4 + (long long)s0 * ROW;
    const float4* h1 = h4 + (long long)s1 * ROW;
#pragma unroll
    for (int j = 0; j < ROWF4; ++j) {
      float4 a = h0[j * 64 + lane];
      float4 b = h1[j * 64 + lane];
      v[j].x += a.x + b.x;
      v[j].y += a.y + b.y;
      v[j].z += a.z + b.z;
      v[j].w += a.w + b.w;
    }
  }
  if (p < pe) {
    int s0 = eidx[p];
    const float4* h0 = h4 + (long long)s0 * ROW;
#pragma unroll
    for (int j = 0; j < ROWF4; ++j) {
      float4 a = h0[j * 64 + lane];
      v[j].x += a.x;
      v[j].y += a.y;
      v[j].z += a.z;
      v[j].w += a.w;
    }
  }
  float4* zn = z4 + (long long)n * ROW;
#pragma unroll
  for (int j = 0; j < ROWF4; ++j) zn[j * 64 + lane] = v[j];
}

// ------------------------------------------------- fp32 GEMM: C = act(A[NxK] @ W[KxM] + bias), M=512
__global__ __launch_bounds__(256) void gemm_bias_act(const float* __restrict__ A,
                                                     const float* __restrict__ W,
                                                     const float* __restrict__ bias,
                                                     float* __restrict__ C,
                                                     int N, int K, int relu) {
  const int M = HID;
  __shared__ float As[16][68];
  __shared__ float Ws[16][68];
  const int tid = threadIdx.x;
  const int tx = tid & 15, ty = tid >> 4;
  const int row0 = blockIdx.y * 64, col0 = blockIdx.x * 64;
  const int la_n = tid >> 2, la_k = (tid & 3) << 2;
  const int lw_k = tid >> 4, lw_m = (tid & 15) << 2;

  float acc[4][4] = {};

  for (int k0 = 0; k0 < K; k0 += 16) {
    int arow = row0 + la_n;
    float4 av = make_float4(0.f, 0.f, 0.f, 0.f);
    if (arow < N) av = *(const float4*)(A + (long long)arow * K + (k0 + la_k));
    As[la_k + 0][la_n] = av.x;
    As[la_k + 1][la_n] = av.y;
    As[la_k + 2][la_n] = av.z;
    As[la_k + 3][la_n] = av.w;
    float4 wv = *(const float4*)(W + (long long)(k0 + lw_k) * M + (col0 + lw_m));
    *(float4*)&Ws[lw_k][lw_m] = wv;
    __syncthreads();
#pragma unroll
    for (int k = 0; k < 16; ++k) {
      float4 a = *(const float4*)&As[k][ty << 2];
      float4 b = *(const float4*)&Ws[k][tx << 2];
      acc[0][0] += a.x * b.x; acc[0][1] += a.x * b.y; acc[0][2] += a.x * b.z; acc[0][3] += a.x * b.w;
      acc[1][0] += a.y * b.x; acc[1][1] += a.y * b.y; acc[1][2] += a.y * b.z; acc[1][3] += a.y * b.w;
      acc[2][0] += a.z * b.x; acc[2][1] += a.z * b.y; acc[2][2] += a.z * b.z; acc[2][3] += a.z * b.w;
      acc[3][0] += a.w * b.x; acc[3][1] += a.w * b.y; acc[3][2] += a.w * b.z; acc[3][3] += a.w * b.w;
    }
    __syncthreads();
  }

  const int cbase = col0 + (tx << 2);
  float4 bv = *(const float4*)(bias + cbase);
#pragma unroll
  for (int i = 0; i < 4; ++i) {
    int r = row0 + (ty << 2) + i;
    if (r >= N) break;
    float4 o;
    o.x = acc[i][0] + bv.x;
    o.y = acc[i][1] + bv.y;
    o.z = acc[i][2] + bv.z;
    o.w = acc[i][3] + bv.w;
    if (relu) {
      o.x = fmaxf(o.x, 0.f); o.y = fmaxf(o.y, 0.f);
      o.z = fmaxf(o.z, 0.f); o.w = fmaxf(o.w, 0.f);
    }
    *(float4*)(C + (long long)r * M + cbase) = o;
  }
}

// ------------------------------------------------- BN statistics (sum, sumsq per channel)
__global__ __launch_bounds__(256) void bn_stats(const float* __restrict__ z,
                                                float* __restrict__ sum,
                                                float* __restrict__ sumsq) {
  const int tid = threadIdx.x;
  const int c0 = tid, c1 = tid + 256;
  float s0 = 0.f, q0 = 0.f, s1 = 0.f, q1 = 0.f;
  for (int n = blockIdx.x; n < N_NODES; n += gridDim.x) {
    float v0 = z[(long long)n * HID + c0];
    float v1 = z[(long long)n * HID + c1];
    s0 += v0; q0 += v0 * v0;
    s1 += v1; q1 += v1 * v1;
  }
  atomicAdd(&sum[c0], s0);
  atomicAdd(&sumsq[c0], q0);
  atomicAdd(&sum[c1], s1);
  atomicAdd(&sumsq[c1], q1);
}

// ------------------------------------------------- BN apply + affine + relu
__global__ __launch_bounds__(256) void bn_apply(const float4* __restrict__ z,
                                                const float* __restrict__ sum,
                                                const float* __restrict__ sumsq,
                                                const float4* __restrict__ g4,
                                                const float4* __restrict__ b4,
                                                float4* __restrict__ h) {
  const float invN = 1.0f / (float)N_NODES;
  const int total4 = N_NODES * (HID / 4);
  for (int i = blockIdx.x * 256 + threadIdx.x; i < total4; i += gridDim.x * 256) {
    int c = i & 127;
    float4 s = ((const float4*)sum)[c];
    float4 q = ((const float4*)sumsq)[c];
    float4 gg = g4[c];
    float4 bb = b4[c];
    float4 zv = z[i];
    float4 o;
    float mu, var, sc;
    mu = s.x * invN; var = q.x * invN - mu * mu; sc = rsqrtf(var + BN_EPS) * gg.x;
    o.x = fmaxf((zv.x - mu) * sc + bb.x, 0.f);
    mu = s.y * invN; var = q.y * invN - mu * mu; sc = rsqrtf(var + BN_EPS) * gg.y;
    o.y = fmaxf((zv.y - mu) * sc + bb.y, 0.f);
    mu = s.z * invN; var = q.z * invN - mu * mu; sc = rsqrtf(var + BN_EPS) * gg.z;
    o.z = fmaxf((zv.z - mu) * sc + bb.z, 0.f);
    mu = s.w * invN; var = q.w * invN - mu * mu; sc = rsqrtf(var + BN_EPS) * gg.w;
    o.w = fmaxf((zv.w - mu) * sc + bb.w, 0.f);
    h[i] = o;
  }
}

// ------------------------------------------------- global add pool (atomic scatter)
__global__ __launch_bounds__(256) void gpool_kernel(const float* __restrict__ h,
                                                    const int* __restrict__ batch,
                                                    float* __restrict__ gp) {
  const int total = N_NODES * (HID / 4);
  for (int i = blockIdx.x * 256 + threadIdx.x; i < total; i += gridDim.x * 256) {
    int n = i >> 7;
    int c = i & 127;
    int g = batch[n];
    float4 v = ((const float4*)(h + (long long)n * HID))[c];
    float* p = gp + (long long)g * HID + c * 4;
    atomicAdd(p + 0, v.x);
    atomicAdd(p + 1, v.y);
    atomicAdd(p + 2, v.z);
    atomicAdd(p + 3, v.w);
  }
}

// ------------------------------------------------- classifier tail
__global__ __launch_bounds__(64) void clf2_softmax(const float* __restrict__ hidden,
                                                   const float* __restrict__ w2,
                                                   const float* __restrict__ b2,
                                                   float* __restrict__ out) {
  const int g = blockIdx.x;      // 512 graphs
  const int lane = threadIdx.x;  // 64
  float acc[10];
#pragma unroll
  for (int j = 0; j < 10; ++j) acc[j] = 0.f;
  for (int k = lane; k < HID; k += 64) {
    float hv = hidden[(long long)g * HID + k];
#pragma unroll
    for (int j = 0; j < 10; ++j) acc[j] += hv * w2[k * 10 + j];
  }
#pragma unroll
  for (int j = 0; j < 10; ++j) {
    for (int off = 32; off > 0; off >>= 1) acc[j] += __shfl_down(acc[j], off);
  }
  if (lane == 0) {
    float lg[10], pb[10];
    float mx = -1e30f;
#pragma unroll
    for (int j = 0; j < 10; ++j) {
      lg[j] = acc[j] + b2[j];
      mx = fmaxf(mx, lg[j]);
    }
    float se = 0.f;
#pragma unroll
    for (int j = 0; j < 10; ++j) {
      pb[j] = __expf(lg[j] - mx);
      se += pb[j];
    }
    float inv = 1.f / se;
    int am = 0;
    float best = lg[0];
#pragma unroll
    for (int j = 1; j < 10; ++j) {
      if (lg[j] > best) { best = lg[j]; am = j; }
    }
#pragma unroll
    for (int j = 0; j < 10; ++j) out[g * 10 + j] = lg[j];
#pragma unroll
    for (int j = 0; j < 10; ++j) out[N_GRAPHS * 10 + g * 10 + j] = pb[j] * inv;
    out[2 * N_GRAPHS * 10 + g] = (float)am;
#pragma unroll
    for (int j = 0; j < 10; ++j)
      out[2 * N_GRAPHS * 10 + N_GRAPHS + g * 10 + j] = (j == am) ? 1.f : 0.f;
  }
}

// ----------------------------------------------------------------- launch
extern "C" void kernel_launch(void* const* d_in, const int* in_sizes, int n_in,
                              void* d_out, int out_size, void* d_ws, size_t ws_size,
                              hipStream_t stream) {
  const float* x = (const float*)d_in[0];
  const int* src = (const int*)d_in[1];
  const int* dstE = src + N_EDGES;
  const int* batch = (const int*)d_in[2];
  const float* w0a = (const float*)d_in[3];
  const float* b0a = (const float*)d_in[4];
  const float* w0b = (const float*)d_in[5];
  const float* b0b = (const float*)d_in[6];
  const float* w1a = (const float*)d_in[7];
  const float* b1a = (const float*)d_in[8];
  const float* w1b = (const float*)d_in[9];
  const float* b1b = (const float*)d_in[10];
  const float* w2a = (const float*)d_in[11];
  const float* b2a = (const float*)d_in[12];
  const float* w2b = (const float*)d_in[13];
  const float* b2b = (const float*)d_in[14];
  const float* bng[3] = {(const float*)d_in[15], (const float*)d_in[17], (const float*)d_in[19]};
  const float* bnb[3] = {(const float*)d_in[16], (const float*)d_in[18], (const float*)d_in[20]};
  const float* clf_w1 = (const float*)d_in[21];
  const float* clf_b1 = (const float*)d_in[22];
  const float* clf_w2 = (const float*)d_in[23];
  const float* clf_b2 = (const float*)d_in[24];
  float* out = (float*)d_out;

  // Workspace layout — 2x [N_NODES x HID] fp32 (~205 MB) + CSR (~3.6 MB) + small tails.
  float* bufA = (float*)d_ws;                        // z / z2
  float* bufB = bufA + (long long)N_NODES * HID;     // z1 / h'
  float* bnsum = bufB + (long long)N_NODES * HID;    // 512
  float* bnsq = bnsum + HID;                         // 512
  float* gp = bnsq + HID;                            // 512*512
  float* hidden = gp + (long long)N_GRAPHS * HID;    // 512*512
  int* deg = (int*)(hidden + (long long)N_GRAPHS * HID);  // 50000 (doubles as scratch)
  int* off = deg + N_NODES;                          // 50001
  int* cursor = off + N_NODES + 1;                   // 50000
  int* eidx = cursor + N_NODES;                      // 800000

  // ---- build CSR (dst -> list of src), once per call
  hipMemsetAsync(deg, 0, N_NODES * sizeof(int), stream);
  hipLaunchKernelGGL(hist_dst, dim3(3125), dim3(256), 0, stream, dstE, deg);
  hipLaunchKernelGGL(scan_deg, dim3(1), dim3(1024), 0, stream, deg, off, cursor);
  hipLaunchKernelGGL(fill_csr, dim3(3125), dim3(256), 0, stream, src, dstE, cursor, eidx);

  const float* wa[3] = {w0a, w1a, w2a};
  const float* ba[3] = {b0a, b1a, b2a};
  const float* wb[3] = {w0b, w1b, w2b};
  const float* bb[3] = {b0b, b1b, b2b};

  const float* h = x;
  int D = IN_DIM;
  for (int layer = 0; layer < 3; ++layer) {
    // z = h + sum_{neighbors} h  -> bufA
    if (D == IN_DIM) {
      hipLaunchKernelGGL((agg_csr<1>), dim3((N_NODES + 3) / 4), dim3(256), 0, stream,
                         (const float4*)h, off, eidx, (float4*)bufA);
    } else {
      hipLaunchKernelGGL((agg_csr<2>), dim3((N_NODES + 3) / 4), dim3(256), 0, stream,
                         (const float4*)h, off, eidx, (float4*)bufA);
    }
    // z1 = relu(z @ wa + ba)
    hipLaunchKernelGGL(gemm_bias_act, dim3(8, (N_NODES + 63) / 64), dim3(256), 0, stream,
                       bufA, wa[layer], ba[layer], bufB, N_NODES, D, 1);
    // z2 = z1 @ wb + bb
    hipLaunchKernelGGL(gemm_bias_act, dim3(8, (N_NODES + 63) / 64), dim3(256), 0, stream,
                       bufB, wb[layer], bb[layer], bufA, N_NODES, HID, 0);
    // batchnorm: stats over bufA, apply -> bufB
    hipMemsetAsync(bnsum, 0, 2 * HID * sizeof(float), stream);
    hipLaunchKernelGGL(bn_stats, dim3(512), dim3(256), 0, stream, bufA, bnsum, bnsq);
    hipLaunchKernelGGL(bn_apply, dim3(4096), dim3(256), 0, stream,
                       (const float4*)bufA, bnsum, bnsq,
                       (const float4*)bng[layer], (const float4*)bnb[layer], (float4*)bufB);
    h = bufB;
    D = HID;
  }

  // global add pool
  hipMemsetAsync(gp, 0, (size_t)N_GRAPHS * HID * sizeof(float), stream);
  hipLaunchKernelGGL(gpool_kernel, dim3(2048), dim3(256), 0, stream, bufB, batch, gp);
  // classifier layer 1
  hipLaunchKernelGGL(gemm_bias_act, dim3(8, 8), dim3(256), 0, stream,
                     gp, clf_w1, clf_b1, hidden, N_GRAPHS, HID, 1);
  // classifier layer 2 + softmax + argmax + one_hot
  hipLaunchKernelGGL(clf2_softmax, dim3(N_GRAPHS), dim3(64), 0, stream,
                     hidden, clf_w2, clf_b2, out);
}

// Round 4
// 2438.244 us; speedup vs baseline: 6.7344x; 1.4944x over previous
//
#include <hip/hip_runtime.h>

#define N_NODES 50000
#define N_EDGES 800000
#define N_GRAPHS 512
#define IN_DIM 256
#define HID 512
#define BN_EPS 1e-5f

typedef __attribute__((ext_vector_type(8))) short bf16x8;
typedef __attribute__((ext_vector_type(4))) float f32x4;

__device__ inline void split_bf16(float a, unsigned short& hi, unsigned short& lo) {
  unsigned u = __float_as_uint(a);
  hi = (unsigned short)(u >> 16);
  float fh = __uint_as_float(u & 0xFFFF0000u);
  float r = a - fh;
  lo = (unsigned short)(__float_as_uint(r) >> 16);
}

// ------------------------------------------------- CSR build: histogram of dst
__global__ __launch_bounds__(256) void hist_dst(const int* __restrict__ dst,
                                                int* __restrict__ deg) {
  for (int e = blockIdx.x * 256 + threadIdx.x; e < N_EDGES; e += gridDim.x * 256)
    atomicAdd(&deg[dst[e]], 1);
}

// ------------------------------------------------- CSR build: exclusive scan (single block)
__global__ __launch_bounds__(1024) void scan_deg(const int* __restrict__ deg,
                                                 int* __restrict__ off,
                                                 int* __restrict__ cursor) {
  __shared__ int partial[1024];
  const int t = threadIdx.x;
  const int CHUNK = 49;
  const int base = t * CHUNK;
  int mysum = 0;
  for (int i = 0; i < CHUNK; ++i) {
    int idx = base + i;
    if (idx < N_NODES) mysum += deg[idx];
  }
  partial[t] = mysum;
  __syncthreads();
  for (int st = 1; st < 1024; st <<= 1) {
    int v = (t >= st) ? partial[t - st] : 0;
    __syncthreads();
    partial[t] += v;
    __syncthreads();
  }
  int run = partial[t] - mysum;
  for (int i = 0; i < CHUNK; ++i) {
    int idx = base + i;
    if (idx < N_NODES) {
      off[idx] = run;
      cursor[idx] = run;
      run += deg[idx];
    }
  }
  if (t == 1023) off[N_NODES] = N_EDGES;
}

// ------------------------------------------------- CSR build: fill edge lists
__global__ __launch_bounds__(256) void fill_csr(const int* __restrict__ src,
                                                const int* __restrict__ dst,
                                                int* __restrict__ cursor,
                                                int* __restrict__ eidx) {
  for (int e = blockIdx.x * 256 + threadIdx.x; e < N_EDGES; e += gridDim.x * 256) {
    int p = atomicAdd(&cursor[dst[e]], 1);
    eidx[p] = src[e];
  }
}

// ------------------------------------------------- gather-aggregate: z[n] = h[n] + sum_{s in N(n)} h[s]
template <int ROWF4>
__global__ __launch_bounds__(256) void agg_csr(const float4* __restrict__ h4,
                                               const int* __restrict__ off,
                                               const int* __restrict__ eidx,
                                               float4* __restrict__ z4) {
  const int n = blockIdx.x * 4 + (threadIdx.x >> 6);
  if (n >= N_NODES) return;
  const int lane = threadIdx.x & 63;
  const int ROW = ROWF4 * 64;
  float4 v[ROWF4];
  const float4* hn = h4 + (long long)n * ROW;
#pragma unroll
  for (int j = 0; j < ROWF4; ++j) v[j] = hn[j * 64 + lane];

  int p = off[n];
  const int pe = off[n + 1];
  for (; p + 2 <= pe; p += 2) {
    int s0 = eidx[p], s1 = eidx[p + 1];
    const float4* h0 = h4 + (long long)s0 * ROW;
    const float4* h1 = h4 + (long long)s1 * ROW;
#pragma unroll
    for (int j = 0; j < ROWF4; ++j) {
      float4 a = h0[j * 64 + lane];
      float4 b = h1[j * 64 + lane];
      v[j].x += a.x + b.x;
      v[j].y += a.y + b.y;
      v[j].z += a.z + b.z;
      v[j].w += a.w + b.w;
    }
  }
  if (p < pe) {
    int s0 = eidx[p];
    const float4* h0 = h4 + (long long)s0 * ROW;
#pragma unroll
    for (int j = 0; j < ROWF4; ++j) {
      float4 a = h0[j * 64 + lane];
      v[j].x += a.x;
      v[j].y += a.y;
      v[j].z += a.z;
      v[j].w += a.w;
    }
  }
  float4* zn = z4 + (long long)n * ROW;
#pragma unroll
  for (int j = 0; j < ROWF4; ++j) zn[j * 64 + lane] = v[j];
}

// ------------------------------------------------- W pre-pack: transpose + split + fragment order
// Wp layout: [bx(2)][ks(K/32)] blocks of 16384 ushorts: hi[8192] then lo[8192];
// within 8192: cf(16)*512 + q(4)*128 + c(16)*8 + j(8); chan=bx*256+cf*16+c, k=ks*32+q*8+j.
__global__ __launch_bounds__(256) void wt_build(const float* __restrict__ W, // [K][512]
                                                unsigned short* __restrict__ Wp,
                                                int KS) {
  int gid = blockIdx.x * 256 + threadIdx.x;
  int total = 2 * KS * 8192;
  if (gid >= total) return;
  int blk = gid >> 13;
  int rem = gid & 8191;
  int cf = rem >> 9;
  int q = (rem >> 7) & 3;
  int c = (rem >> 3) & 15;
  int j = rem & 7;
  int bx = blk / KS, ks = blk - bx * KS;
  int chan = bx * 256 + cf * 16 + c;
  int k = ks * 32 + q * 8 + j;
  float v = W[(size_t)k * 512 + chan];
  unsigned short h, l;
  split_bf16(v, h, l);
  Wp[(size_t)blk * 16384 + rem] = h;
  Wp[(size_t)blk * 16384 + 8192 + rem] = l;
}

// ------------------------------------------------- split-bf16 MFMA GEMM
// C[N x 512] = act(A[N x K] @ W + bias); W given as packed Wp (transposed+split).
// Block: 256 thr / 4 waves; tile 64 nodes x 256 chans x K32 steps.
__global__ __launch_bounds__(256) void gemm_mfma(const float4* __restrict__ A4, // [N][K/4]
                                                 const unsigned short* __restrict__ Wp,
                                                 const float* __restrict__ bias,
                                                 float* __restrict__ C, // [N][512]
                                                 int N, int K, int relu) {
  __shared__ unsigned short Wl[16384]; // hi[0:8192) lo[8192:16384)
  __shared__ unsigned short Al[4096];  // hi[0:2048) lo[2048:4096)
  const int tid = threadIdx.x;
  const int wv = tid >> 6, ln = tid & 63;
  const int bx = blockIdx.x;       // chan super-block (0/1)
  const int n0 = blockIdx.y * 64;  // node base
  const int KS = K >> 5;
  const int K4 = K >> 2;

  f32x4 acc[4][4];
#pragma unroll
  for (int i = 0; i < 4; ++i)
#pragma unroll
    for (int j = 0; j < 4; ++j) acc[i][j] = f32x4{0.f, 0.f, 0.f, 0.f};

  const int f0 = tid * 2;
  const int nd0 = f0 >> 3;   // node-in-tile 0..63
  const int k40 = f0 & 7;    // first f4-chunk (k40, k40+1)
  const bool arow_ok = (n0 + nd0) < N;
  const int nf = nd0 >> 4, ccs = nd0 & 15;

  const unsigned short* wsrc = Wp + (size_t)bx * KS * 16384;

  for (int ks = 0; ks < KS; ++ks) {
    // stage W: contiguous 32KB copy (fragment-ordered in global already)
    {
      const unsigned short* ws = wsrc + (size_t)ks * 16384;
#pragma unroll
      for (int cpy = 0; cpy < 8; ++cpy) {
        int off8 = (cpy * 256 + tid) * 8;
        *(uint4*)&Wl[off8] = *(const uint4*)&ws[off8];
      }
    }
    // stage A: 64 nodes x 32 k fp32 -> hi/lo bf16 fragment-ordered
    {
      const float4* arow = A4 + (size_t)(n0 + nd0) * K4 + ks * 8;
#pragma unroll
      for (int t = 0; t < 2; ++t) {
        int k4 = k40 + t;
        float4 av = make_float4(0.f, 0.f, 0.f, 0.f);
        if (arow_ok) av = arow[k4];
        unsigned short h0, h1, h2, h3, l0, l1, l2, l3;
        split_bf16(av.x, h0, l0);
        split_bf16(av.y, h1, l1);
        split_bf16(av.z, h2, l2);
        split_bf16(av.w, h3, l3);
        int q = k4 >> 1, r = k4 & 1;
        int soff = nf * 512 + q * 128 + ccs * 8 + r * 4;
        uint2 hv, lv;
        hv.x = (unsigned)h0 | ((unsigned)h1 << 16);
        hv.y = (unsigned)h2 | ((unsigned)h3 << 16);
        lv.x = (unsigned)l0 | ((unsigned)l1 << 16);
        lv.y = (unsigned)l2 | ((unsigned)l3 << 16);
        *(uint2*)&Al[soff] = hv;
        *(uint2*)&Al[2048 + soff] = lv;
      }
    }
    __syncthreads();
    // compute: D += Wt_frag (Aop) x Act_frag (Bop); 3-term split product
    bf16x8 wh[4], wlo[4], ah[4], alo[4];
#pragma unroll
    for (int i = 0; i < 4; ++i) {
      int base = (wv * 4 + i) * 512 + ln * 8;
      wh[i] = *(const bf16x8*)&Wl[base];
      wlo[i] = *(const bf16x8*)&Wl[8192 + base];
    }
#pragma unroll
    for (int j = 0; j < 4; ++j) {
      int base = j * 512 + ln * 8;
      ah[j] = *(const bf16x8*)&Al[base];
      alo[j] = *(const bf16x8*)&Al[2048 + base];
    }
#pragma unroll
    for (int i = 0; i < 4; ++i)
#pragma unroll
      for (int j = 0; j < 4; ++j) {
        acc[i][j] = __builtin_amdgcn_mfma_f32_16x16x32_bf16(wh[i], ah[j], acc[i][j], 0, 0, 0);
        acc[i][j] = __builtin_amdgcn_mfma_f32_16x16x32_bf16(wh[i], alo[j], acc[i][j], 0, 0, 0);
        acc[i][j] = __builtin_amdgcn_mfma_f32_16x16x32_bf16(wlo[i], ah[j], acc[i][j], 0, 0, 0);
      }
    __syncthreads();
  }

  // epilogue: D row = chan-in-frag ((ln>>4)*4+reg), col = node-in-frag (ln&15)
  const int chanb = bx * 256 + wv * 64 + (ln >> 4) * 4;
#pragma unroll
  for (int j = 0; j < 4; ++j) {
    int node = n0 + j * 16 + (ln & 15);
    if (node >= N) continue;
#pragma unroll
    for (int i = 0; i < 4; ++i) {
      int chan = chanb + i * 16;
      float4 bv = *(const float4*)(bias + chan);
      f32x4 a = acc[i][j];
      float4 o;
      o.x = a[0] + bv.x;
      o.y = a[1] + bv.y;
      o.z = a[2] + bv.z;
      o.w = a[3] + bv.w;
      if (relu) {
        o.x = fmaxf(o.x, 0.f);
        o.y = fmaxf(o.y, 0.f);
        o.z = fmaxf(o.z, 0.f);
        o.w = fmaxf(o.w, 0.f);
      }
      *(float4*)(C + (size_t)node * 512 + chan) = o;
    }
  }
}

// ------------------------------------------------- BN statistics
__global__ __launch_bounds__(256) void bn_stats(const float* __restrict__ z,
                                                float* __restrict__ sum,
                                                float* __restrict__ sumsq) {
  const int tid = threadIdx.x;
  const int c0 = tid, c1 = tid + 256;
  float s0 = 0.f, q0 = 0.f, s1 = 0.f, q1 = 0.f;
  for (int n = blockIdx.x; n < N_NODES; n += gridDim.x) {
    float v0 = z[(long long)n * HID + c0];
    float v1 = z[(long long)n * HID + c1];
    s0 += v0; q0 += v0 * v0;
    s1 += v1; q1 += v1 * v1;
  }
  atomicAdd(&sum[c0], s0);
  atomicAdd(&sumsq[c0], q0);
  atomicAdd(&sum[c1], s1);
  atomicAdd(&sumsq[c1], q1);
}

// ------------------------------------------------- BN apply + affine + relu
__global__ __launch_bounds__(256) void bn_apply(const float4* __restrict__ z,
                                                const float* __restrict__ sum,
                                                const float* __restrict__ sumsq,
                                                const float4* __restrict__ g4,
                                                const float4* __restrict__ b4,
                                                float4* __restrict__ h) {
  const float invN = 1.0f / (float)N_NODES;
  const int total4 = N_NODES * (HID / 4);
  for (int i = blockIdx.x * 256 + threadIdx.x; i < total4; i += gridDim.x * 256) {
    int c = i & 127;
    float4 s = ((const float4*)sum)[c];
    float4 q = ((const float4*)sumsq)[c];
    float4 gg = g4[c];
    float4 bb = b4[c];
    float4 zv = z[i];
    float4 o;
    float mu, var, sc;
    mu = s.x * invN; var = q.x * invN - mu * mu; sc = rsqrtf(var + BN_EPS) * gg.x;
    o.x = fmaxf((zv.x - mu) * sc + bb.x, 0.f);
    mu = s.y * invN; var = q.y * invN - mu * mu; sc = rsqrtf(var + BN_EPS) * gg.y;
    o.y = fmaxf((zv.y - mu) * sc + bb.y, 0.f);
    mu = s.z * invN; var = q.z * invN - mu * mu; sc = rsqrtf(var + BN_EPS) * gg.z;
    o.z = fmaxf((zv.z - mu) * sc + bb.z, 0.f);
    mu = s.w * invN; var = q.w * invN - mu * mu; sc = rsqrtf(var + BN_EPS) * gg.w;
    o.w = fmaxf((zv.w - mu) * sc + bb.w, 0.f);
    h[i] = o;
  }
}

// ------------------------------------------------- global add pool
__global__ __launch_bounds__(256) void gpool_kernel(const float* __restrict__ h,
                                                    const int* __restrict__ batch,
                                                    float* __restrict__ gp) {
  const int total = N_NODES * (HID / 4);
  for (int i = blockIdx.x * 256 + threadIdx.x; i < total; i += gridDim.x * 256) {
    int n = i >> 7;
    int c = i & 127;
    int g = batch[n];
    float4 v = ((const float4*)(h + (long long)n * HID))[c];
    float* p = gp + (long long)g * HID + c * 4;
    atomicAdd(p + 0, v.x);
    atomicAdd(p + 1, v.y);
    atomicAdd(p + 2, v.z);
    atomicAdd(p + 3, v.w);
  }
}

// ------------------------------------------------- classifier tail
__global__ __launch_bounds__(64) void clf2_softmax(const float* __restrict__ hidden,
                                                   const float* __restrict__ w2,
                                                   const float* __restrict__ b2,
                                                   float* __restrict__ out) {
  const int g = blockIdx.x;
  const int lane = threadIdx.x;
  float acc[10];
#pragma unroll
  for (int j = 0; j < 10; ++j) acc[j] = 0.f;
  for (int k = lane; k < HID; k += 64) {
    float hv = hidden[(long long)g * HID + k];
#pragma unroll
    for (int j = 0; j < 10; ++j) acc[j] += hv * w2[k * 10 + j];
  }
#pragma unroll
  for (int j = 0; j < 10; ++j) {
    for (int o = 32; o > 0; o >>= 1) acc[j] += __shfl_down(acc[j], o);
  }
  if (lane == 0) {
    float lg[10], pb[10];
    float mx = -1e30f;
#pragma unroll
    for (int j = 0; j < 10; ++j) {
      lg[j] = acc[j] + b2[j];
      mx = fmaxf(mx, lg[j]);
    }
    float se = 0.f;
#pragma unroll
    for (int j = 0; j < 10; ++j) {
      pb[j] = __expf(lg[j] - mx);
      se += pb[j];
    }
    float inv = 1.f / se;
    int am = 0;
    float best = lg[0];
#pragma unroll
    for (int j = 1; j < 10; ++j) {
      if (lg[j] > best) { best = lg[j]; am = j; }
    }
#pragma unroll
    for (int j = 0; j < 10; ++j) out[g * 10 + j] = lg[j];
#pragma unroll
    for (int j = 0; j < 10; ++j) out[N_GRAPHS * 10 + g * 10 + j] = pb[j] * inv;
    out[2 * N_GRAPHS * 10 + g] = (float)am;
#pragma unroll
    for (int j = 0; j < 10; ++j)
      out[2 * N_GRAPHS * 10 + N_GRAPHS + g * 10 + j] = (j == am) ? 1.f : 0.f;
  }
}

// ----------------------------------------------------------------- launch
extern "C" void kernel_launch(void* const* d_in, const int* in_sizes, int n_in,
                              void* d_out, int out_size, void* d_ws, size_t ws_size,
                              hipStream_t stream) {
  const float* x = (const float*)d_in[0];
  const int* src = (const int*)d_in[1];
  const int* dstE = src + N_EDGES;
  const int* batch = (const int*)d_in[2];
  const float* w0a = (const float*)d_in[3];
  const float* b0a = (const float*)d_in[4];
  const float* w0b = (const float*)d_in[5];
  const float* b0b = (const float*)d_in[6];
  const float* w1a = (const float*)d_in[7];
  const float* b1a = (const float*)d_in[8];
  const float* w1b = (const float*)d_in[9];
  const float* b1b = (const float*)d_in[10];
  const float* w2a = (const float*)d_in[11];
  const float* b2a = (const float*)d_in[12];
  const float* w2b = (const float*)d_in[13];
  const float* b2b = (const float*)d_in[14];
  const float* bng[3] = {(const float*)d_in[15], (const float*)d_in[17], (const float*)d_in[19]};
  const float* bnb[3] = {(const float*)d_in[16], (const float*)d_in[18], (const float*)d_in[20]};
  const float* clf_w1 = (const float*)d_in[21];
  const float* clf_b1 = (const float*)d_in[22];
  const float* clf_w2 = (const float*)d_in[23];
  const float* clf_b2 = (const float*)d_in[24];
  float* out = (float*)d_out;

  // ---- workspace layout (~217.5 MB)
  float* bufA = (float*)d_ws;
  float* bufB = bufA + 25600000LL;
  float* bnsum = bufB + 25600000LL;
  float* bnsq = bnsum + 512;
  float* gp = bnsq + 512;
  float* hidden = gp + 262144;
  // packed weights (16B-aligned here: float offset is a multiple of 4)
  unsigned short* wp0a = (unsigned short*)(hidden + 262144);  // K=256: 262144 ushorts
  unsigned short* wp0b = wp0a + 262144;                       // K=512: 524288 each
  unsigned short* wp1a = wp0b + 524288;
  unsigned short* wp1b = wp1a + 524288;
  unsigned short* wp2a = wp1b + 524288;
  unsigned short* wp2b = wp2a + 524288;
  unsigned short* wpc1 = wp2b + 524288;
  int* deg = (int*)(wpc1 + 524288);
  int* off = deg + N_NODES;
  int* cursor = off + N_NODES + 1;
  int* eidx = cursor + N_NODES;

  // ---- build CSR (dst -> list of src)
  hipMemsetAsync(deg, 0, N_NODES * sizeof(int), stream);
  hipLaunchKernelGGL(hist_dst, dim3(3125), dim3(256), 0, stream, dstE, deg);
  hipLaunchKernelGGL(scan_deg, dim3(1), dim3(1024), 0, stream, deg, off, cursor);
  hipLaunchKernelGGL(fill_csr, dim3(3125), dim3(256), 0, stream, src, dstE, cursor, eidx);

  // ---- pre-pack all weights (transpose + split + fragment order)
  hipLaunchKernelGGL(wt_build, dim3(512), dim3(256), 0, stream, w0a, wp0a, 8);
  hipLaunchKernelGGL(wt_build, dim3(1024), dim3(256), 0, stream, w0b, wp0b, 16);
  hipLaunchKernelGGL(wt_build, dim3(1024), dim3(256), 0, stream, w1a, wp1a, 16);
  hipLaunchKernelGGL(wt_build, dim3(1024), dim3(256), 0, stream, w1b, wp1b, 16);
  hipLaunchKernelGGL(wt_build, dim3(1024), dim3(256), 0, stream, w2a, wp2a, 16);
  hipLaunchKernelGGL(wt_build, dim3(1024), dim3(256), 0, stream, w2b, wp2b, 16);
  hipLaunchKernelGGL(wt_build, dim3(1024), dim3(256), 0, stream, clf_w1, wpc1, 16);

  const unsigned short* wpa[3] = {wp0a, wp1a, wp2a};
  const unsigned short* wpb[3] = {wp0b, wp1b, wp2b};
  const float* ba[3] = {b0a, b1a, b2a};
  const float* bb[3] = {b0b, b1b, b2b};

  const float* h = x;
  int D = IN_DIM;
  const int nby = (N_NODES + 63) / 64;
  for (int layer = 0; layer < 3; ++layer) {
    // z = h + sum_neighbors h -> bufA
    if (D == IN_DIM) {
      hipLaunchKernelGGL((agg_csr<1>), dim3((N_NODES + 3) / 4), dim3(256), 0, stream,
                         (const float4*)h, off, eidx, (float4*)bufA);
    } else {
      hipLaunchKernelGGL((agg_csr<2>), dim3((N_NODES + 3) / 4), dim3(256), 0, stream,
                         (const float4*)h, off, eidx, (float4*)bufA);
    }
    // z1 = relu(z @ wa + ba) -> bufB
    hipLaunchKernelGGL(gemm_mfma, dim3(2, nby), dim3(256), 0, stream,
                       (const float4*)bufA, wpa[layer], ba[layer], bufB, N_NODES, D, 1);
    // z2 = z1 @ wb + bb -> bufA
    hipLaunchKernelGGL(gemm_mfma, dim3(2, nby), dim3(256), 0, stream,
                       (const float4*)bufB, wpb[layer], bb[layer], bufA, N_NODES, HID, 0);
    // batchnorm: stats over bufA, apply -> bufB
    hipMemsetAsync(bnsum, 0, 2 * HID * sizeof(float), stream);
    hipLaunchKernelGGL(bn_stats, dim3(512), dim3(256), 0, stream, bufA, bnsum, bnsq);
    hipLaunchKernelGGL(bn_apply, dim3(4096), dim3(256), 0, stream,
                       (const float4*)bufA, bnsum, bnsq,
                       (const float4*)bng[layer], (const float4*)bnb[layer], (float4*)bufB);
    h = bufB;
    D = HID;
  }

  // global add pool
  hipMemsetAsync(gp, 0, (size_t)N_GRAPHS * HID * sizeof(float), stream);
  hipLaunchKernelGGL(gpool_kernel, dim3(2048), dim3(256), 0, stream, bufB, batch, gp);
  // classifier layer 1 (N=512 rows)
  hipLaunchKernelGGL(gemm_mfma, dim3(2, 8), dim3(256), 0, stream,
                     (const float4*)gp, wpc1, clf_b1, hidden, N_GRAPHS, HID, 1);
  // classifier layer 2 + softmax + argmax + one_hot
  hipLaunchKernelGGL(clf2_softmax, dim3(N_GRAPHS), dim3(64), 0, stream,
                     hidden, clf_w2, clf_b2, out);
}

// Round 5
// 2149.552 us; speedup vs baseline: 7.6388x; 1.1343x over previous
//
#include <hip/hip_runtime.h>

#define N_NODES 50000
#define N_EDGES 800000
#define N_GRAPHS 512
#define IN_DIM 256
#define HID 512
#define BN_EPS 1e-5f

typedef __attribute__((ext_vector_type(8))) short bf16x8;
typedef __attribute__((ext_vector_type(4))) float f32x4;

__device__ inline void split_bf16(float a, unsigned short& hi, unsigned short& lo) {
  unsigned u = __float_as_uint(a);
  hi = (unsigned short)(u >> 16);
  float fh = __uint_as_float(u & 0xFFFF0000u);
  float r = a - fh;
  lo = (unsigned short)(__float_as_uint(r) >> 16);
}

// ------------------------------------------------- CSR build: histogram of dst
__global__ __launch_bounds__(256) void hist_dst(const int* __restrict__ dst,
                                                int* __restrict__ deg) {
  for (int e = blockIdx.x * 256 + threadIdx.x; e < N_EDGES; e += gridDim.x * 256)
    atomicAdd(&deg[dst[e]], 1);
}

// ------------------------------------------------- CSR build: exclusive scan (single block)
__global__ __launch_bounds__(1024) void scan_deg(const int* __restrict__ deg,
                                                 int* __restrict__ off,
                                                 int* __restrict__ cursor) {
  __shared__ int partial[1024];
  const int t = threadIdx.x;
  const int CHUNK = 49;
  const int base = t * CHUNK;
  int mysum = 0;
  for (int i = 0; i < CHUNK; ++i) {
    int idx = base + i;
    if (idx < N_NODES) mysum += deg[idx];
  }
  partial[t] = mysum;
  __syncthreads();
  for (int st = 1; st < 1024; st <<= 1) {
    int v = (t >= st) ? partial[t - st] : 0;
    __syncthreads();
    partial[t] += v;
    __syncthreads();
  }
  int run = partial[t] - mysum;
  for (int i = 0; i < CHUNK; ++i) {
    int idx = base + i;
    if (idx < N_NODES) {
      off[idx] = run;
      cursor[idx] = run;
      run += deg[idx];
    }
  }
  if (t == 1023) off[N_NODES] = N_EDGES;
}

// ------------------------------------------------- CSR build: fill edge lists
__global__ __launch_bounds__(256) void fill_csr(const int* __restrict__ src,
                                                const int* __restrict__ dst,
                                                int* __restrict__ cursor,
                                                int* __restrict__ eidx) {
  for (int e = blockIdx.x * 256 + threadIdx.x; e < N_EDGES; e += gridDim.x * 256) {
    int p = atomicAdd(&cursor[dst[e]], 1);
    eidx[p] = src[e];
  }
}

// ------------------------------------------------- gather-aggregate: z[n] = h[n] + sum_{s in N(n)} h[s]
template <int ROWF4>
__global__ __launch_bounds__(256) void agg_csr(const float4* __restrict__ h4,
                                               const int* __restrict__ off,
                                               const int* __restrict__ eidx,
                                               float4* __restrict__ z4) {
  const int n = blockIdx.x * 4 + (threadIdx.x >> 6);
  if (n >= N_NODES) return;
  const int lane = threadIdx.x & 63;
  const int ROW = ROWF4 * 64;
  float4 v[ROWF4];
  const float4* hn = h4 + (long long)n * ROW;
#pragma unroll
  for (int j = 0; j < ROWF4; ++j) v[j] = hn[j * 64 + lane];

  int p = off[n];
  const int pe = off[n + 1];
  for (; p + 2 <= pe; p += 2) {
    int s0 = eidx[p], s1 = eidx[p + 1];
    const float4* h0 = h4 + (long long)s0 * ROW;
    const float4* h1 = h4 + (long long)s1 * ROW;
#pragma unroll
    for (int j = 0; j < ROWF4; ++j) {
      float4 a = h0[j * 64 + lane];
      float4 b = h1[j * 64 + lane];
      v[j].x += a.x + b.x;
      v[j].y += a.y + b.y;
      v[j].z += a.z + b.z;
      v[j].w += a.w + b.w;
    }
  }
  if (p < pe) {
    int s0 = eidx[p];
    const float4* h0 = h4 + (long long)s0 * ROW;
#pragma unroll
    for (int j = 0; j < ROWF4; ++j) {
      float4 a = h0[j * 64 + lane];
      v[j].x += a.x;
      v[j].y += a.y;
      v[j].z += a.z;
      v[j].w += a.w;
    }
  }
  float4* zn = z4 + (long long)n * ROW;
#pragma unroll
  for (int j = 0; j < ROWF4; ++j) zn[j * 64 + lane] = v[j];
}

// ------------------------------------------------- W pre-pack: transpose + split + fragment order
__global__ __launch_bounds__(256) void wt_build(const float* __restrict__ W, // [K][512]
                                                unsigned short* __restrict__ Wp,
                                                int KS) {
  int gid = blockIdx.x * 256 + threadIdx.x;
  int total = 2 * KS * 8192;
  if (gid >= total) return;
  int blk = gid >> 13;
  int rem = gid & 8191;
  int cf = rem >> 9;
  int q = (rem >> 7) & 3;
  int c = (rem >> 3) & 15;
  int j = rem & 7;
  int bx = blk / KS, ks = blk - bx * KS;
  int chan = bx * 256 + cf * 16 + c;
  int k = ks * 32 + q * 8 + j;
  float v = W[(size_t)k * 512 + chan];
  unsigned short h, l;
  split_bf16(v, h, l);
  Wp[(size_t)blk * 16384 + rem] = h;
  Wp[(size_t)blk * 16384 + 8192 + rem] = l;
}

// ------------------------------------------------- split-bf16 MFMA GEMM
__global__ __launch_bounds__(256) void gemm_mfma(const float4* __restrict__ A4, // [N][K/4]
                                                 const unsigned short* __restrict__ Wp,
                                                 const float* __restrict__ bias,
                                                 float* __restrict__ C, // [N][512]
                                                 int N, int K, int relu) {
  __shared__ unsigned short Wl[16384]; // hi[0:8192) lo[8192:16384)
  __shared__ unsigned short Al[4096];  // hi[0:2048) lo[2048:4096)
  const int tid = threadIdx.x;
  const int wv = tid >> 6, ln = tid & 63;
  const int bx = blockIdx.x;       // chan super-block (0/1)
  const int n0 = blockIdx.y * 64;  // node base
  const int KS = K >> 5;
  const int K4 = K >> 2;

  f32x4 acc[4][4];
#pragma unroll
  for (int i = 0; i < 4; ++i)
#pragma unroll
    for (int j = 0; j < 4; ++j) acc[i][j] = f32x4{0.f, 0.f, 0.f, 0.f};

  const int f0 = tid * 2;
  const int nd0 = f0 >> 3;
  const int k40 = f0 & 7;
  const bool arow_ok = (n0 + nd0) < N;
  const int nf = nd0 >> 4, ccs = nd0 & 15;

  const unsigned short* wsrc = Wp + (size_t)bx * KS * 16384;

  for (int ks = 0; ks < KS; ++ks) {
    {
      const unsigned short* ws = wsrc + (size_t)ks * 16384;
#pragma unroll
      for (int cpy = 0; cpy < 8; ++cpy) {
        int off8 = (cpy * 256 + tid) * 8;
        *(uint4*)&Wl[off8] = *(const uint4*)&ws[off8];
      }
    }
    {
      const float4* arow = A4 + (size_t)(n0 + nd0) * K4 + ks * 8;
#pragma unroll
      for (int t = 0; t < 2; ++t) {
        int k4 = k40 + t;
        float4 av = make_float4(0.f, 0.f, 0.f, 0.f);
        if (arow_ok) av = arow[k4];
        unsigned short h0, h1, h2, h3, l0, l1, l2, l3;
        split_bf16(av.x, h0, l0);
        split_bf16(av.y, h1, l1);
        split_bf16(av.z, h2, l2);
        split_bf16(av.w, h3, l3);
        int q = k4 >> 1, r = k4 & 1;
        int soff = nf * 512 + q * 128 + ccs * 8 + r * 4;
        uint2 hv, lv;
        hv.x = (unsigned)h0 | ((unsigned)h1 << 16);
        hv.y = (unsigned)h2 | ((unsigned)h3 << 16);
        lv.x = (unsigned)l0 | ((unsigned)l1 << 16);
        lv.y = (unsigned)l2 | ((unsigned)l3 << 16);
        *(uint2*)&Al[soff] = hv;
        *(uint2*)&Al[2048 + soff] = lv;
      }
    }
    __syncthreads();
    bf16x8 wh[4], wlo[4], ah[4], alo[4];
#pragma unroll
    for (int i = 0; i < 4; ++i) {
      int base = (wv * 4 + i) * 512 + ln * 8;
      wh[i] = *(const bf16x8*)&Wl[base];
      wlo[i] = *(const bf16x8*)&Wl[8192 + base];
    }
#pragma unroll
    for (int j = 0; j < 4; ++j) {
      int base = j * 512 + ln * 8;
      ah[j] = *(const bf16x8*)&Al[base];
      alo[j] = *(const bf16x8*)&Al[2048 + base];
    }
#pragma unroll
    for (int i = 0; i < 4; ++i)
#pragma unroll
      for (int j = 0; j < 4; ++j) {
        acc[i][j] = __builtin_amdgcn_mfma_f32_16x16x32_bf16(wh[i], ah[j], acc[i][j], 0, 0, 0);
        acc[i][j] = __builtin_amdgcn_mfma_f32_16x16x32_bf16(wh[i], alo[j], acc[i][j], 0, 0, 0);
        acc[i][j] = __builtin_amdgcn_mfma_f32_16x16x32_bf16(wlo[i], ah[j], acc[i][j], 0, 0, 0);
      }
    __syncthreads();
  }

  const int chanb = bx * 256 + wv * 64 + (ln >> 4) * 4;
#pragma unroll
  for (int j = 0; j < 4; ++j) {
    int node = n0 + j * 16 + (ln & 15);
    if (node >= N) continue;
#pragma unroll
    for (int i = 0; i < 4; ++i) {
      int chan = chanb + i * 16;
      float4 bv = *(const float4*)(bias + chan);
      f32x4 a = acc[i][j];
      float4 o;
      o.x = a[0] + bv.x;
      o.y = a[1] + bv.y;
      o.z = a[2] + bv.z;
      o.w = a[3] + bv.w;
      if (relu) {
        o.x = fmaxf(o.x, 0.f);
        o.y = fmaxf(o.y, 0.f);
        o.z = fmaxf(o.z, 0.f);
        o.w = fmaxf(o.w, 0.f);
      }
      *(float4*)(C + (size_t)node * 512 + chan) = o;
    }
  }
}

// ------------------------------------------------- BN statistics
__global__ __launch_bounds__(256) void bn_stats(const float* __restrict__ z,
                                                float* __restrict__ sum,
                                                float* __restrict__ sumsq) {
  const int tid = threadIdx.x;
  const int c0 = tid, c1 = tid + 256;
  float s0 = 0.f, q0 = 0.f, s1 = 0.f, q1 = 0.f;
  for (int n = blockIdx.x; n < N_NODES; n += gridDim.x) {
    float v0 = z[(long long)n * HID + c0];
    float v1 = z[(long long)n * HID + c1];
    s0 += v0; q0 += v0 * v0;
    s1 += v1; q1 += v1 * v1;
  }
  atomicAdd(&sum[c0], s0);
  atomicAdd(&sumsq[c0], q0);
  atomicAdd(&sum[c1], s1);
  atomicAdd(&sumsq[c1], q1);
}

// ------------------------------------------------- BN apply + affine + relu
__global__ __launch_bounds__(256) void bn_apply(const float4* __restrict__ z,
                                                const float* __restrict__ sum,
                                                const float* __restrict__ sumsq,
                                                const float4* __restrict__ g4,
                                                const float4* __restrict__ b4,
                                                float4* __restrict__ h) {
  const float invN = 1.0f / (float)N_NODES;
  const int total4 = N_NODES * (HID / 4);
  for (int i = blockIdx.x * 256 + threadIdx.x; i < total4; i += gridDim.x * 256) {
    int c = i & 127;
    float4 s = ((const float4*)sum)[c];
    float4 q = ((const float4*)sumsq)[c];
    float4 gg = g4[c];
    float4 bb = b4[c];
    float4 zv = z[i];
    float4 o;
    float mu, var, sc;
    mu = s.x * invN; var = q.x * invN - mu * mu; sc = rsqrtf(var + BN_EPS) * gg.x;
    o.x = fmaxf((zv.x - mu) * sc + bb.x, 0.f);
    mu = s.y * invN; var = q.y * invN - mu * mu; sc = rsqrtf(var + BN_EPS) * gg.y;
    o.y = fmaxf((zv.y - mu) * sc + bb.y, 0.f);
    mu = s.z * invN; var = q.z * invN - mu * mu; sc = rsqrtf(var + BN_EPS) * gg.z;
    o.z = fmaxf((zv.z - mu) * sc + bb.z, 0.f);
    mu = s.w * invN; var = q.w * invN - mu * mu; sc = rsqrtf(var + BN_EPS) * gg.w;
    o.w = fmaxf((zv.w - mu) * sc + bb.w, 0.f);
    h[i] = o;
  }
}

// ------------------------------------------------- pool bounds: start[g] = lower_bound(batch, g)
__global__ __launch_bounds__(512) void pool_bounds(const int* __restrict__ batch,
                                                   int* __restrict__ gstart) {
  const int g = threadIdx.x;  // 0..511
  int lo = 0, hi = N_NODES;
  while (lo < hi) {
    int mid = (lo + hi) >> 1;
    if (batch[mid] < g) lo = mid + 1;
    else hi = mid;
  }
  gstart[g] = lo;
  if (g == 0) gstart[N_GRAPHS] = N_NODES;
}

// ------------------------------------------------- segmented global add pool (batch sorted)
__global__ __launch_bounds__(128) void gpool_seg(const float4* __restrict__ h4,
                                                 const int* __restrict__ gstart,
                                                 float4* __restrict__ gp4) {
  const int g = blockIdx.x;
  const int t = threadIdx.x;  // 0..127 -> float4 chunk
  const int s = gstart[g], e = gstart[g + 1];
  float4 acc = make_float4(0.f, 0.f, 0.f, 0.f);
  for (int n = s; n < e; ++n) {
    float4 v = h4[(size_t)n * 128 + t];
    acc.x += v.x;
    acc.y += v.y;
    acc.z += v.z;
    acc.w += v.w;
  }
  gp4[(size_t)g * 128 + t] = acc;
}

// ------------------------------------------------- classifier tail
__global__ __launch_bounds__(64) void clf2_softmax(const float* __restrict__ hidden,
                                                   const float* __restrict__ w2,
                                                   const float* __restrict__ b2,
                                                   float* __restrict__ out) {
  const int g = blockIdx.x;
  const int lane = threadIdx.x;
  float acc[10];
#pragma unroll
  for (int j = 0; j < 10; ++j) acc[j] = 0.f;
  for (int k = lane; k < HID; k += 64) {
    float hv = hidden[(long long)g * HID + k];
#pragma unroll
    for (int j = 0; j < 10; ++j) acc[j] += hv * w2[k * 10 + j];
  }
#pragma unroll
  for (int j = 0; j < 10; ++j) {
    for (int o = 32; o > 0; o >>= 1) acc[j] += __shfl_down(acc[j], o);
  }
  if (lane == 0) {
    float lg[10], pb[10];
    float mx = -1e30f;
#pragma unroll
    for (int j = 0; j < 10; ++j) {
      lg[j] = acc[j] + b2[j];
      mx = fmaxf(mx, lg[j]);
    }
    float se = 0.f;
#pragma unroll
    for (int j = 0; j < 10; ++j) {
      pb[j] = __expf(lg[j] - mx);
      se += pb[j];
    }
    float inv = 1.f / se;
    int am = 0;
    float best = lg[0];
#pragma unroll
    for (int j = 1; j < 10; ++j) {
      if (lg[j] > best) { best = lg[j]; am = j; }
    }
#pragma unroll
    for (int j = 0; j < 10; ++j) out[g * 10 + j] = lg[j];
#pragma unroll
    for (int j = 0; j < 10; ++j) out[N_GRAPHS * 10 + g * 10 + j] = pb[j] * inv;
    out[2 * N_GRAPHS * 10 + g] = (float)am;
#pragma unroll
    for (int j = 0; j < 10; ++j)
      out[2 * N_GRAPHS * 10 + N_GRAPHS + g * 10 + j] = (j == am) ? 1.f : 0.f;
  }
}

// ----------------------------------------------------------------- launch
extern "C" void kernel_launch(void* const* d_in, const int* in_sizes, int n_in,
                              void* d_out, int out_size, void* d_ws, size_t ws_size,
                              hipStream_t stream) {
  const float* x = (const float*)d_in[0];
  const int* src = (const int*)d_in[1];
  const int* dstE = src + N_EDGES;
  const int* batch = (const int*)d_in[2];
  const float* w0a = (const float*)d_in[3];
  const float* b0a = (const float*)d_in[4];
  const float* w0b = (const float*)d_in[5];
  const float* b0b = (const float*)d_in[6];
  const float* w1a = (const float*)d_in[7];
  const float* b1a = (const float*)d_in[8];
  const float* w1b = (const float*)d_in[9];
  const float* b1b = (const float*)d_in[10];
  const float* w2a = (const float*)d_in[11];
  const float* b2a = (const float*)d_in[12];
  const float* w2b = (const float*)d_in[13];
  const float* b2b = (const float*)d_in[14];
  const float* bng[3] = {(const float*)d_in[15], (const float*)d_in[17], (const float*)d_in[19]};
  const float* bnb[3] = {(const float*)d_in[16], (const float*)d_in[18], (const float*)d_in[20]};
  const float* clf_w1 = (const float*)d_in[21];
  const float* clf_b1 = (const float*)d_in[22];
  const float* clf_w2 = (const float*)d_in[23];
  const float* clf_b2 = (const float*)d_in[24];
  float* out = (float*)d_out;

  // ---- workspace layout (~217.5 MB)
  float* bufA = (float*)d_ws;
  float* bufB = bufA + 25600000LL;
  float* bnsum = bufB + 25600000LL;
  float* bnsq = bnsum + 512;
  float* gp = bnsq + 512;
  float* hidden = gp + 262144;
  unsigned short* wp0a = (unsigned short*)(hidden + 262144);
  unsigned short* wp0b = wp0a + 262144;
  unsigned short* wp1a = wp0b + 524288;
  unsigned short* wp1b = wp1a + 524288;
  unsigned short* wp2a = wp1b + 524288;
  unsigned short* wp2b = wp2a + 524288;
  unsigned short* wpc1 = wp2b + 524288;
  int* deg = (int*)(wpc1 + 524288);
  int* off = deg + N_NODES;
  int* cursor = off + N_NODES + 1;
  int* eidx = cursor + N_NODES;
  int* gstart = eidx + N_EDGES;  // 513

  // ---- build CSR (dst -> list of src)
  hipMemsetAsync(deg, 0, N_NODES * sizeof(int), stream);
  hipLaunchKernelGGL(hist_dst, dim3(3125), dim3(256), 0, stream, dstE, deg);
  hipLaunchKernelGGL(scan_deg, dim3(1), dim3(1024), 0, stream, deg, off, cursor);
  hipLaunchKernelGGL(fill_csr, dim3(3125), dim3(256), 0, stream, src, dstE, cursor, eidx);
  hipLaunchKernelGGL(pool_bounds, dim3(1), dim3(512), 0, stream, batch, gstart);

  // ---- pre-pack all weights
  hipLaunchKernelGGL(wt_build, dim3(512), dim3(256), 0, stream, w0a, wp0a, 8);
  hipLaunchKernelGGL(wt_build, dim3(1024), dim3(256), 0, stream, w0b, wp0b, 16);
  hipLaunchKernelGGL(wt_build, dim3(1024), dim3(256), 0, stream, w1a, wp1a, 16);
  hipLaunchKernelGGL(wt_build, dim3(1024), dim3(256), 0, stream, w1b, wp1b, 16);
  hipLaunchKernelGGL(wt_build, dim3(1024), dim3(256), 0, stream, w2a, wp2a, 16);
  hipLaunchKernelGGL(wt_build, dim3(1024), dim3(256), 0, stream, w2b, wp2b, 16);
  hipLaunchKernelGGL(wt_build, dim3(1024), dim3(256), 0, stream, clf_w1, wpc1, 16);

  const unsigned short* wpa[3] = {wp0a, wp1a, wp2a};
  const unsigned short* wpb[3] = {wp0b, wp1b, wp2b};
  const float* ba[3] = {b0a, b1a, b2a};
  const float* bb[3] = {b0b, b1b, b2b};

  const float* h = x;
  int D = IN_DIM;
  const int nby = (N_NODES + 63) / 64;
  for (int layer = 0; layer < 3; ++layer) {
    if (D == IN_DIM) {
      hipLaunchKernelGGL((agg_csr<1>), dim3((N_NODES + 3) / 4), dim3(256), 0, stream,
                         (const float4*)h, off, eidx, (float4*)bufA);
    } else {
      hipLaunchKernelGGL((agg_csr<2>), dim3((N_NODES + 3) / 4), dim3(256), 0, stream,
                         (const float4*)h, off, eidx, (float4*)bufA);
    }
    hipLaunchKernelGGL(gemm_mfma, dim3(2, nby), dim3(256), 0, stream,
                       (const float4*)bufA, wpa[layer], ba[layer], bufB, N_NODES, D, 1);
    hipLaunchKernelGGL(gemm_mfma, dim3(2, nby), dim3(256), 0, stream,
                       (const float4*)bufB, wpb[layer], bb[layer], bufA, N_NODES, HID, 0);
    hipMemsetAsync(bnsum, 0, 2 * HID * sizeof(float), stream);
    hipLaunchKernelGGL(bn_stats, dim3(512), dim3(256), 0, stream, bufA, bnsum, bnsq);
    hipLaunchKernelGGL(bn_apply, dim3(4096), dim3(256), 0, stream,
                       (const float4*)bufA, bnsum, bnsq,
                       (const float4*)bng[layer], (const float4*)bnb[layer], (float4*)bufB);
    h = bufB;
    D = HID;
  }

  // segmented global add pool (batch is sorted)
  hipLaunchKernelGGL(gpool_seg, dim3(N_GRAPHS), dim3(128), 0, stream,
                     (const float4*)bufB, gstart, (float4*)gp);
  // classifier layer 1 (N=512 rows)
  hipLaunchKernelGGL(gemm_mfma, dim3(2, 8), dim3(256), 0, stream,
                     (const float4*)gp, wpc1, clf_b1, hidden, N_GRAPHS, HID, 1);
  // classifier layer 2 + softmax + argmax + one_hot
  hipLaunchKernelGGL(clf2_softmax, dim3(N_GRAPHS), dim3(64), 0, stream,
                     hidden, clf_w2, clf_b2, out);
}

// Round 6
// 2050.913 us; speedup vs baseline: 8.0062x; 1.0481x over previous
//
#include <hip/hip_runtime.h>

#define N_NODES 50000
#define N_EDGES 800000
#define N_GRAPHS 512
#define IN_DIM 256
#define HID 512
#define BN_EPS 1e-5f

typedef __attribute__((ext_vector_type(8))) short bf16x8;
typedef __attribute__((ext_vector_type(4))) float f32x4;

__device__ inline void split_bf16(float a, unsigned short& hi, unsigned short& lo) {
  unsigned u = __float_as_uint(a);
  hi = (unsigned short)(u >> 16);
  float fh = __uint_as_float(u & 0xFFFF0000u);
  float r = a - fh;
  lo = (unsigned short)(__float_as_uint(r) >> 16);
}

__device__ inline float4 bnrelu4(float4 v, float4 s, float4 h) {
  float4 o;
  o.x = fmaxf(fmaf(v.x, s.x, h.x), 0.f);
  o.y = fmaxf(fmaf(v.y, s.y, h.y), 0.f);
  o.z = fmaxf(fmaf(v.z, s.z, h.z), 0.f);
  o.w = fmaxf(fmaf(v.w, s.w, h.w), 0.f);
  return o;
}

// ------------------------------------------------- CSR build: histogram of dst
__global__ __launch_bounds__(256) void hist_dst(const int* __restrict__ dst,
                                                int* __restrict__ deg) {
  for (int e = blockIdx.x * 256 + threadIdx.x; e < N_EDGES; e += gridDim.x * 256)
    atomicAdd(&deg[dst[e]], 1);
}

// ------------------------------------------------- CSR build: exclusive scan (single block)
__global__ __launch_bounds__(1024) void scan_deg(const int* __restrict__ deg,
                                                 int* __restrict__ off,
                                                 int* __restrict__ cursor) {
  __shared__ int partial[1024];
  const int t = threadIdx.x;
  const int CHUNK = 49;
  const int base = t * CHUNK;
  int mysum = 0;
  for (int i = 0; i < CHUNK; ++i) {
    int idx = base + i;
    if (idx < N_NODES) mysum += deg[idx];
  }
  partial[t] = mysum;
  __syncthreads();
  for (int st = 1; st < 1024; st <<= 1) {
    int v = (t >= st) ? partial[t - st] : 0;
    __syncthreads();
    partial[t] += v;
    __syncthreads();
  }
  int run = partial[t] - mysum;
  for (int i = 0; i < CHUNK; ++i) {
    int idx = base + i;
    if (idx < N_NODES) {
      off[idx] = run;
      cursor[idx] = run;
      run += deg[idx];
    }
  }
  if (t == 1023) off[N_NODES] = N_EDGES;
}

// ------------------------------------------------- CSR build: fill edge lists
__global__ __launch_bounds__(256) void fill_csr(const int* __restrict__ src,
                                                const int* __restrict__ dst,
                                                int* __restrict__ cursor,
                                                int* __restrict__ eidx) {
  for (int e = blockIdx.x * 256 + threadIdx.x; e < N_EDGES; e += gridDim.x * 256) {
    int p = atomicAdd(&cursor[dst[e]], 1);
    eidx[p] = src[e];
  }
}

// ------------------------------------------------- gather-aggregate (+ optional fused BN+relu on loads)
// z[n] = f(h[n]) + sum_{s in N(n)} f(h[s]),  f = identity or relu(v*scale+shift)
template <int ROWF4, int HASBN>
__global__ __launch_bounds__(256) void agg_csr(const float4* __restrict__ h4,
                                               const int* __restrict__ off,
                                               const int* __restrict__ eidx,
                                               const float4* __restrict__ scale4,
                                               const float4* __restrict__ shift4,
                                               float4* __restrict__ z4) {
  const int n = blockIdx.x * 4 + (threadIdx.x >> 6);
  if (n >= N_NODES) return;
  const int lane = threadIdx.x & 63;
  const int ROW = ROWF4 * 64;
  float4 sc[ROWF4], sh[ROWF4];
  if (HASBN) {
#pragma unroll
    for (int j = 0; j < ROWF4; ++j) {
      sc[j] = scale4[j * 64 + lane];
      sh[j] = shift4[j * 64 + lane];
    }
  }
  float4 v[ROWF4];
  const float4* hn = h4 + (long long)n * ROW;
#pragma unroll
  for (int j = 0; j < ROWF4; ++j) {
    float4 a = hn[j * 64 + lane];
    v[j] = HASBN ? bnrelu4(a, sc[j], sh[j]) : a;
  }

  int p = off[n];
  const int pe = off[n + 1];
  for (; p + 4 <= pe; p += 4) {
    int s0 = eidx[p], s1 = eidx[p + 1], s2 = eidx[p + 2], s3 = eidx[p + 3];
    const float4* h0 = h4 + (long long)s0 * ROW;
    const float4* h1 = h4 + (long long)s1 * ROW;
    const float4* h2 = h4 + (long long)s2 * ROW;
    const float4* h3 = h4 + (long long)s3 * ROW;
#pragma unroll
    for (int j = 0; j < ROWF4; ++j) {
      float4 a = h0[j * 64 + lane];
      float4 b = h1[j * 64 + lane];
      float4 c = h2[j * 64 + lane];
      float4 d = h3[j * 64 + lane];
      if (HASBN) {
        a = bnrelu4(a, sc[j], sh[j]);
        b = bnrelu4(b, sc[j], sh[j]);
        c = bnrelu4(c, sc[j], sh[j]);
        d = bnrelu4(d, sc[j], sh[j]);
      }
      v[j].x += (a.x + b.x) + (c.x + d.x);
      v[j].y += (a.y + b.y) + (c.y + d.y);
      v[j].z += (a.z + b.z) + (c.z + d.z);
      v[j].w += (a.w + b.w) + (c.w + d.w);
    }
  }
  for (; p < pe; ++p) {
    int s0 = eidx[p];
    const float4* h0 = h4 + (long long)s0 * ROW;
#pragma unroll
    for (int j = 0; j < ROWF4; ++j) {
      float4 a = h0[j * 64 + lane];
      if (HASBN) a = bnrelu4(a, sc[j], sh[j]);
      v[j].x += a.x;
      v[j].y += a.y;
      v[j].z += a.z;
      v[j].w += a.w;
    }
  }
  float4* zn = z4 + (long long)n * ROW;
#pragma unroll
  for (int j = 0; j < ROWF4; ++j) zn[j * 64 + lane] = v[j];
}

// ------------------------------------------------- W pre-pack: transpose + split + fragment order
__global__ __launch_bounds__(256) void wt_build(const float* __restrict__ W, // [K][512]
                                                unsigned short* __restrict__ Wp,
                                                int KS) {
  int gid = blockIdx.x * 256 + threadIdx.x;
  int total = 2 * KS * 8192;
  if (gid >= total) return;
  int blk = gid >> 13;
  int rem = gid & 8191;
  int cf = rem >> 9;
  int q = (rem >> 7) & 3;
  int c = (rem >> 3) & 15;
  int j = rem & 7;
  int bx = blk / KS, ks = blk - bx * KS;
  int chan = bx * 256 + cf * 16 + c;
  int k = ks * 32 + q * 8 + j;
  float v = W[(size_t)k * 512 + chan];
  unsigned short h, l;
  split_bf16(v, h, l);
  Wp[(size_t)blk * 16384 + rem] = h;
  Wp[(size_t)blk * 16384 + 8192 + rem] = l;
}

// ------------------------------------------------- split-bf16 MFMA GEMM (+ optional fused BN stats)
template <int STATS>
__global__ __launch_bounds__(256) void gemm_mfma(const float4* __restrict__ A4, // [N][K/4]
                                                 const unsigned short* __restrict__ Wp,
                                                 const float* __restrict__ bias,
                                                 float* __restrict__ C, // [N][512]
                                                 float* __restrict__ stat_sum,
                                                 float* __restrict__ stat_sq,
                                                 int N, int K, int relu) {
  __shared__ unsigned short Wl[16384]; // hi[0:8192) lo[8192:16384)
  __shared__ unsigned short Al[4096];  // hi[0:2048) lo[2048:4096)
  const int tid = threadIdx.x;
  const int wv = tid >> 6, ln = tid & 63;
  const int bx = blockIdx.x;       // chan super-block (0/1)
  const int n0 = blockIdx.y * 64;  // node base
  const int KS = K >> 5;
  const int K4 = K >> 2;

  f32x4 acc[4][4];
#pragma unroll
  for (int i = 0; i < 4; ++i)
#pragma unroll
    for (int j = 0; j < 4; ++j) acc[i][j] = f32x4{0.f, 0.f, 0.f, 0.f};

  const int f0 = tid * 2;
  const int nd0 = f0 >> 3;
  const int k40 = f0 & 7;
  const bool arow_ok = (n0 + nd0) < N;
  const int nf = nd0 >> 4, ccs = nd0 & 15;

  const unsigned short* wsrc = Wp + (size_t)bx * KS * 16384;

  for (int ks = 0; ks < KS; ++ks) {
    {
      const unsigned short* ws = wsrc + (size_t)ks * 16384;
#pragma unroll
      for (int cpy = 0; cpy < 8; ++cpy) {
        int off8 = (cpy * 256 + tid) * 8;
        *(uint4*)&Wl[off8] = *(const uint4*)&ws[off8];
      }
    }
    {
      const float4* arow = A4 + (size_t)(n0 + nd0) * K4 + ks * 8;
#pragma unroll
      for (int t = 0; t < 2; ++t) {
        int k4 = k40 + t;
        float4 av = make_float4(0.f, 0.f, 0.f, 0.f);
        if (arow_ok) av = arow[k4];
        unsigned short h0, h1, h2, h3, l0, l1, l2, l3;
        split_bf16(av.x, h0, l0);
        split_bf16(av.y, h1, l1);
        split_bf16(av.z, h2, l2);
        split_bf16(av.w, h3, l3);
        int q = k4 >> 1, r = k4 & 1;
        int soff = nf * 512 + q * 128 + ccs * 8 + r * 4;
        uint2 hv, lv;
        hv.x = (unsigned)h0 | ((unsigned)h1 << 16);
        hv.y = (unsigned)h2 | ((unsigned)h3 << 16);
        lv.x = (unsigned)l0 | ((unsigned)l1 << 16);
        lv.y = (unsigned)l2 | ((unsigned)l3 << 16);
        *(uint2*)&Al[soff] = hv;
        *(uint2*)&Al[2048 + soff] = lv;
      }
    }
    __syncthreads();
    bf16x8 wh[4], wlo[4], ah[4], alo[4];
#pragma unroll
    for (int i = 0; i < 4; ++i) {
      int base = (wv * 4 + i) * 512 + ln * 8;
      wh[i] = *(const bf16x8*)&Wl[base];
      wlo[i] = *(const bf16x8*)&Wl[8192 + base];
    }
#pragma unroll
    for (int j = 0; j < 4; ++j) {
      int base = j * 512 + ln * 8;
      ah[j] = *(const bf16x8*)&Al[base];
      alo[j] = *(const bf16x8*)&Al[2048 + base];
    }
#pragma unroll
    for (int i = 0; i < 4; ++i)
#pragma unroll
      for (int j = 0; j < 4; ++j) {
        acc[i][j] = __builtin_amdgcn_mfma_f32_16x16x32_bf16(wh[i], ah[j], acc[i][j], 0, 0, 0);
        acc[i][j] = __builtin_amdgcn_mfma_f32_16x16x32_bf16(wh[i], alo[j], acc[i][j], 0, 0, 0);
        acc[i][j] = __builtin_amdgcn_mfma_f32_16x16x32_bf16(wlo[i], ah[j], acc[i][j], 0, 0, 0);
      }
    __syncthreads();
  }

  const int chanb = bx * 256 + wv * 64 + (ln >> 4) * 4;
  float4 s4[4], q4[4];
  if (STATS) {
#pragma unroll
    for (int i = 0; i < 4; ++i) {
      s4[i] = make_float4(0.f, 0.f, 0.f, 0.f);
      q4[i] = make_float4(0.f, 0.f, 0.f, 0.f);
    }
  }
#pragma unroll
  for (int j = 0; j < 4; ++j) {
    int node = n0 + j * 16 + (ln & 15);
    bool valid = node < N;
#pragma unroll
    for (int i = 0; i < 4; ++i) {
      int chan = chanb + i * 16;
      float4 bv = *(const float4*)(bias + chan);
      f32x4 a = acc[i][j];
      float4 o;
      o.x = a[0] + bv.x;
      o.y = a[1] + bv.y;
      o.z = a[2] + bv.z;
      o.w = a[3] + bv.w;
      if (relu) {
        o.x = fmaxf(o.x, 0.f);
        o.y = fmaxf(o.y, 0.f);
        o.z = fmaxf(o.z, 0.f);
        o.w = fmaxf(o.w, 0.f);
      }
      if (valid) *(float4*)(C + (size_t)node * 512 + chan) = o;
      if (STATS) {
        if (!valid) o = make_float4(0.f, 0.f, 0.f, 0.f);
        s4[i].x += o.x; s4[i].y += o.y; s4[i].z += o.z; s4[i].w += o.w;
        q4[i].x += o.x * o.x; q4[i].y += o.y * o.y;
        q4[i].z += o.z * o.z; q4[i].w += o.w * o.w;
      }
    }
  }
  if (STATS) {
#pragma unroll
    for (int i = 0; i < 4; ++i) {
#pragma unroll
      for (int mask = 1; mask < 16; mask <<= 1) {
        s4[i].x += __shfl_xor(s4[i].x, mask);
        s4[i].y += __shfl_xor(s4[i].y, mask);
        s4[i].z += __shfl_xor(s4[i].z, mask);
        s4[i].w += __shfl_xor(s4[i].w, mask);
        q4[i].x += __shfl_xor(q4[i].x, mask);
        q4[i].y += __shfl_xor(q4[i].y, mask);
        q4[i].z += __shfl_xor(q4[i].z, mask);
        q4[i].w += __shfl_xor(q4[i].w, mask);
      }
    }
    if ((ln & 15) == 0) {
#pragma unroll
      for (int i = 0; i < 4; ++i) {
        int chan = chanb + i * 16;
        atomicAdd(&stat_sum[chan + 0], s4[i].x);
        atomicAdd(&stat_sum[chan + 1], s4[i].y);
        atomicAdd(&stat_sum[chan + 2], s4[i].z);
        atomicAdd(&stat_sum[chan + 3], s4[i].w);
        atomicAdd(&stat_sq[chan + 0], q4[i].x);
        atomicAdd(&stat_sq[chan + 1], q4[i].y);
        atomicAdd(&stat_sq[chan + 2], q4[i].z);
        atomicAdd(&stat_sq[chan + 3], q4[i].w);
      }
    }
  }
}

// ------------------------------------------------- BN finalize: (sum,sumsq,g,b) -> (scale,shift)
__global__ __launch_bounds__(512) void bn_finalize(const float* __restrict__ sum,
                                                   const float* __restrict__ sumsq,
                                                   const float* __restrict__ g,
                                                   const float* __restrict__ b,
                                                   float* __restrict__ scale,
                                                   float* __restrict__ shift) {
  const int c = threadIdx.x;
  const float invN = 1.0f / (float)N_NODES;
  float mu = sum[c] * invN;
  float var = sumsq[c] * invN - mu * mu;
  float sc = rsqrtf(var + BN_EPS) * g[c];
  scale[c] = sc;
  shift[c] = fmaf(-mu, sc, b[c]);
}

// ------------------------------------------------- pool bounds: start[g] = lower_bound(batch, g)
__global__ __launch_bounds__(512) void pool_bounds(const int* __restrict__ batch,
                                                   int* __restrict__ gstart) {
  const int g = threadIdx.x;
  int lo = 0, hi = N_NODES;
  while (lo < hi) {
    int mid = (lo + hi) >> 1;
    if (batch[mid] < g) lo = mid + 1;
    else hi = mid;
  }
  gstart[g] = lo;
  if (g == 0) gstart[N_GRAPHS] = N_NODES;
}

// ------------------------------------------------- segmented global add pool with fused BN+relu
__global__ __launch_bounds__(128) void gpool_bn(const float4* __restrict__ z4,
                                                const int* __restrict__ gstart,
                                                const float4* __restrict__ scale4,
                                                const float4* __restrict__ shift4,
                                                float4* __restrict__ gp4) {
  const int g = blockIdx.x;
  const int t = threadIdx.x;  // 0..127 -> float4 chunk
  const int s = gstart[g], e = gstart[g + 1];
  const float4 sc = scale4[t], sh = shift4[t];
  float4 acc = make_float4(0.f, 0.f, 0.f, 0.f);
  for (int n = s; n < e; ++n) {
    float4 v = bnrelu4(z4[(size_t)n * 128 + t], sc, sh);
    acc.x += v.x;
    acc.y += v.y;
    acc.z += v.z;
    acc.w += v.w;
  }
  gp4[(size_t)g * 128 + t] = acc;
}

// ------------------------------------------------- classifier tail
__global__ __launch_bounds__(64) void clf2_softmax(const float* __restrict__ hidden,
                                                   const float* __restrict__ w2,
                                                   const float* __restrict__ b2,
                                                   float* __restrict__ out) {
  const int g = blockIdx.x;
  const int lane = threadIdx.x;
  float acc[10];
#pragma unroll
  for (int j = 0; j < 10; ++j) acc[j] = 0.f;
  for (int k = lane; k < HID; k += 64) {
    float hv = hidden[(long long)g * HID + k];
#pragma unroll
    for (int j = 0; j < 10; ++j) acc[j] += hv * w2[k * 10 + j];
  }
#pragma unroll
  for (int j = 0; j < 10; ++j) {
    for (int o = 32; o > 0; o >>= 1) acc[j] += __shfl_down(acc[j], o);
  }
  if (lane == 0) {
    float lg[10], pb[10];
    float mx = -1e30f;
#pragma unroll
    for (int j = 0; j < 10; ++j) {
      lg[j] = acc[j] + b2[j];
      mx = fmaxf(mx, lg[j]);
    }
    float se = 0.f;
#pragma unroll
    for (int j = 0; j < 10; ++j) {
      pb[j] = __expf(lg[j] - mx);
      se += pb[j];
    }
    float inv = 1.f / se;
    int am = 0;
    float best = lg[0];
#pragma unroll
    for (int j = 1; j < 10; ++j) {
      if (lg[j] > best) { best = lg[j]; am = j; }
    }
#pragma unroll
    for (int j = 0; j < 10; ++j) out[g * 10 + j] = lg[j];
#pragma unroll
    for (int j = 0; j < 10; ++j) out[N_GRAPHS * 10 + g * 10 + j] = pb[j] * inv;
    out[2 * N_GRAPHS * 10 + g] = (float)am;
#pragma unroll
    for (int j = 0; j < 10; ++j)
      out[2 * N_GRAPHS * 10 + N_GRAPHS + g * 10 + j] = (j == am) ? 1.f : 0.f;
  }
}

// ----------------------------------------------------------------- launch
extern "C" void kernel_launch(void* const* d_in, const int* in_sizes, int n_in,
                              void* d_out, int out_size, void* d_ws, size_t ws_size,
                              hipStream_t stream) {
  const float* x = (const float*)d_in[0];
  const int* src = (const int*)d_in[1];
  const int* dstE = src + N_EDGES;
  const int* batch = (const int*)d_in[2];
  const float* w0a = (const float*)d_in[3];
  const float* b0a = (const float*)d_in[4];
  const float* w0b = (const float*)d_in[5];
  const float* b0b = (const float*)d_in[6];
  const float* w1a = (const float*)d_in[7];
  const float* b1a = (const float*)d_in[8];
  const float* w1b = (const float*)d_in[9];
  const float* b1b = (const float*)d_in[10];
  const float* w2a = (const float*)d_in[11];
  const float* b2a = (const float*)d_in[12];
  const float* w2b = (const float*)d_in[13];
  const float* b2b = (const float*)d_in[14];
  const float* bng[3] = {(const float*)d_in[15], (const float*)d_in[17], (const float*)d_in[19]};
  const float* bnb[3] = {(const float*)d_in[16], (const float*)d_in[18], (const float*)d_in[20]};
  const float* clf_w1 = (const float*)d_in[21];
  const float* clf_b1 = (const float*)d_in[22];
  const float* clf_w2 = (const float*)d_in[23];
  const float* clf_b2 = (const float*)d_in[24];
  float* out = (float*)d_out;

  // ---- workspace layout (~218 MB)
  float* bufA = (float*)d_ws;
  float* bufB = bufA + 25600000LL;
  float* bnsum = bufB + 25600000LL;   // 512
  float* bnsq = bnsum + 512;          // 512
  float* scale = bnsq + 512;          // 512
  float* shift = scale + 512;         // 512
  float* gp = shift + 512;            // 512*512
  float* hidden = gp + 262144;        // 512*512
  unsigned short* wp0a = (unsigned short*)(hidden + 262144);
  unsigned short* wp0b = wp0a + 262144;
  unsigned short* wp1a = wp0b + 524288;
  unsigned short* wp1b = wp1a + 524288;
  unsigned short* wp2a = wp1b + 524288;
  unsigned short* wp2b = wp2a + 524288;
  unsigned short* wpc1 = wp2b + 524288;
  int* deg = (int*)(wpc1 + 524288);
  int* off = deg + N_NODES;
  int* cursor = off + N_NODES + 1;
  int* eidx = cursor + N_NODES;
  int* gstart = eidx + N_EDGES;  // 513

  // ---- build CSR (dst -> list of src) + pool bounds
  hipMemsetAsync(deg, 0, N_NODES * sizeof(int), stream);
  hipLaunchKernelGGL(hist_dst, dim3(3125), dim3(256), 0, stream, dstE, deg);
  hipLaunchKernelGGL(scan_deg, dim3(1), dim3(1024), 0, stream, deg, off, cursor);
  hipLaunchKernelGGL(fill_csr, dim3(3125), dim3(256), 0, stream, src, dstE, cursor, eidx);
  hipLaunchKernelGGL(pool_bounds, dim3(1), dim3(512), 0, stream, batch, gstart);

  // ---- pre-pack all weights
  hipLaunchKernelGGL(wt_build, dim3(512), dim3(256), 0, stream, w0a, wp0a, 8);
  hipLaunchKernelGGL(wt_build, dim3(1024), dim3(256), 0, stream, w0b, wp0b, 16);
  hipLaunchKernelGGL(wt_build, dim3(1024), dim3(256), 0, stream, w1a, wp1a, 16);
  hipLaunchKernelGGL(wt_build, dim3(1024), dim3(256), 0, stream, w1b, wp1b, 16);
  hipLaunchKernelGGL(wt_build, dim3(1024), dim3(256), 0, stream, w2a, wp2a, 16);
  hipLaunchKernelGGL(wt_build, dim3(1024), dim3(256), 0, stream, w2b, wp2b, 16);
  hipLaunchKernelGGL(wt_build, dim3(1024), dim3(256), 0, stream, clf_w1, wpc1, 16);

  const unsigned short* wpa[3] = {wp0a, wp1a, wp2a};
  const unsigned short* wpb[3] = {wp0b, wp1b, wp2b};
  const float* ba[3] = {b0a, b1a, b2a};
  const float* bb[3] = {b0b, b1b, b2b};

  const int nby = (N_NODES + 63) / 64;
  const int nagg = (N_NODES + 3) / 4;

  // Buffers alternate: layer L input zprev in P, z in Q, z1 in P, z2 in Q.
  float* P = bufA;
  float* Q = bufB;
  for (int layer = 0; layer < 3; ++layer) {
    if (layer == 0) {
      // z = x + sum_neighbors x -> bufA  (P=bufA used as z output here)
      hipLaunchKernelGGL((agg_csr<1, 0>), dim3(nagg), dim3(256), 0, stream,
                         (const float4*)x, off, eidx, nullptr, nullptr, (float4*)P);
    } else {
      // z = f(zprev) + sum f(zprev),  f = relu(v*scale+shift); zprev in P -> z in Q; then swap
      hipLaunchKernelGGL((agg_csr<2, 1>), dim3(nagg), dim3(256), 0, stream,
                         (const float4*)P, off, eidx, (const float4*)scale,
                         (const float4*)shift, (float4*)Q);
      float* t = P; P = Q; Q = t;  // now z is in P
    }
    // z1 = relu(z @ wa + ba): P -> Q
    hipLaunchKernelGGL((gemm_mfma<0>), dim3(2, nby), dim3(256), 0, stream,
                       (const float4*)P, wpa[layer], ba[layer], Q, nullptr, nullptr,
                       N_NODES, (layer == 0) ? IN_DIM : HID, 1);
    // z2 = z1 @ wb + bb (+stats): Q -> P
    hipMemsetAsync(bnsum, 0, 2 * 512 * sizeof(float), stream);
    hipLaunchKernelGGL((gemm_mfma<1>), dim3(2, nby), dim3(256), 0, stream,
                       (const float4*)Q, wpb[layer], bb[layer], P, bnsum, bnsq,
                       N_NODES, HID, 0);
    hipLaunchKernelGGL(bn_finalize, dim3(1), dim3(512), 0, stream,
                       bnsum, bnsq, bng[layer], bnb[layer], scale, shift);
    // layer output (pre-BN z2) is in P; scale/shift hold its BN params
  }

  // global add pool with fused BN+relu: P -> gp
  hipLaunchKernelGGL(gpool_bn, dim3(N_GRAPHS), dim3(128), 0, stream,
                     (const float4*)P, gstart, (const float4*)scale,
                     (const float4*)shift, (float4*)gp);
  // classifier layer 1 (N=512 rows)
  hipLaunchKernelGGL((gemm_mfma<0>), dim3(2, 8), dim3(256), 0, stream,
                     (const float4*)gp, wpc1, clf_b1, hidden, nullptr, nullptr,
                     N_GRAPHS, HID, 1);
  // classifier layer 2 + softmax + argmax + one_hot
  hipLaunchKernelGGL(clf2_softmax, dim3(N_GRAPHS), dim3(64), 0, stream,
                     hidden, clf_w2, clf_b2, out);
}

// Round 7
// 1686.522 us; speedup vs baseline: 9.7361x; 1.2161x over previous
//
#include <hip/hip_runtime.h>

#define N_NODES 50000
#define N_EDGES 800000
#define N_GRAPHS 512
#define IN_DIM 256
#define HID 512
#define BN_EPS 1e-5f

typedef __attribute__((ext_vector_type(8))) short bf16x8;
typedef __attribute__((ext_vector_type(4))) float f32x4;

__device__ inline void split_bf16(float a, unsigned short& hi, unsigned short& lo) {
  unsigned u = __float_as_uint(a);
  hi = (unsigned short)(u >> 16);
  float fh = __uint_as_float(u & 0xFFFF0000u);
  float r = a - fh;
  lo = (unsigned short)(__float_as_uint(r) >> 16);
}

// split a float4 into hi/lo bf16 pairs and store as two 8B words
__device__ inline void split4_store(float4 v, unsigned short* hip, unsigned short* lop) {
  unsigned short h0, h1, h2, h3, l0, l1, l2, l3;
  split_bf16(v.x, h0, l0);
  split_bf16(v.y, h1, l1);
  split_bf16(v.z, h2, l2);
  split_bf16(v.w, h3, l3);
  uint2 hv, lv;
  hv.x = (unsigned)h0 | ((unsigned)h1 << 16);
  hv.y = (unsigned)h2 | ((unsigned)h3 << 16);
  lv.x = (unsigned)l0 | ((unsigned)l1 << 16);
  lv.y = (unsigned)l2 | ((unsigned)l3 << 16);
  *(uint2*)hip = hv;
  *(uint2*)lop = lv;
}

__device__ inline float4 bnrelu4(float4 v, float4 s, float4 h) {
  float4 o;
  o.x = fmaxf(fmaf(v.x, s.x, h.x), 0.f);
  o.y = fmaxf(fmaf(v.y, s.y, h.y), 0.f);
  o.z = fmaxf(fmaf(v.z, s.z, h.z), 0.f);
  o.w = fmaxf(fmaf(v.w, s.w, h.w), 0.f);
  return o;
}

// ------------------------------------------------- CSR build: histogram of dst
__global__ __launch_bounds__(256) void hist_dst(const int* __restrict__ dst,
                                                int* __restrict__ deg) {
  for (int e = blockIdx.x * 256 + threadIdx.x; e < N_EDGES; e += gridDim.x * 256)
    atomicAdd(&deg[dst[e]], 1);
}

// ------------------------------------------------- CSR build: exclusive scan (single block)
__global__ __launch_bounds__(1024) void scan_deg(const int* __restrict__ deg,
                                                 int* __restrict__ off,
                                                 int* __restrict__ cursor) {
  __shared__ int partial[1024];
  const int t = threadIdx.x;
  const int CHUNK = 49;
  const int base = t * CHUNK;
  int mysum = 0;
  for (int i = 0; i < CHUNK; ++i) {
    int idx = base + i;
    if (idx < N_NODES) mysum += deg[idx];
  }
  partial[t] = mysum;
  __syncthreads();
  for (int st = 1; st < 1024; st <<= 1) {
    int v = (t >= st) ? partial[t - st] : 0;
    __syncthreads();
    partial[t] += v;
    __syncthreads();
  }
  int run = partial[t] - mysum;
  for (int i = 0; i < CHUNK; ++i) {
    int idx = base + i;
    if (idx < N_NODES) {
      off[idx] = run;
      cursor[idx] = run;
      run += deg[idx];
    }
  }
  if (t == 1023) off[N_NODES] = N_EDGES;
}

// ------------------------------------------------- CSR build: fill edge lists
__global__ __launch_bounds__(256) void fill_csr(const int* __restrict__ src,
                                                const int* __restrict__ dst,
                                                int* __restrict__ cursor,
                                                int* __restrict__ eidx) {
  for (int e = blockIdx.x * 256 + threadIdx.x; e < N_EDGES; e += gridDim.x * 256) {
    int p = atomicAdd(&cursor[dst[e]], 1);
    eidx[p] = src[e];
  }
}

// ------------------------------------------------- gather-aggregate -> PACKED fragment output
// z[n] = f(h[n]) + sum_{s in N(n)} f(h[s]); f = identity or relu(v*scale+shift).
// Output layout per (tile=n/64, ks): 4096 ushorts, hi[0:2048) lo[2048:4096),
// slot = nf*512 + q*128 + ccs*8 + r*4 (nf=(n%64)/16, ccs=n%16, q=(k4>>1), r=(k4&1), k4=chunk%8).
template <int ROWF4, int HASBN>
__global__ __launch_bounds__(256) void agg_pk(const float4* __restrict__ h4,
                                              const int* __restrict__ off,
                                              const int* __restrict__ eidx,
                                              const float4* __restrict__ scale4,
                                              const float4* __restrict__ shift4,
                                              unsigned short* __restrict__ zp) {
  const int n = blockIdx.x * 4 + (threadIdx.x >> 6);
  if (n >= N_NODES) return;
  const int lane = threadIdx.x & 63;
  const int ROW = ROWF4 * 64;
  float4 sc[ROWF4], sh[ROWF4];
  if (HASBN) {
#pragma unroll
    for (int j = 0; j < ROWF4; ++j) {
      sc[j] = scale4[j * 64 + lane];
      sh[j] = shift4[j * 64 + lane];
    }
  }
  float4 v[ROWF4];
  const float4* hn = h4 + (long long)n * ROW;
#pragma unroll
  for (int j = 0; j < ROWF4; ++j) {
    float4 a = hn[j * 64 + lane];
    v[j] = HASBN ? bnrelu4(a, sc[j], sh[j]) : a;
  }

  int p = off[n];
  const int pe = off[n + 1];
  for (; p + 4 <= pe; p += 4) {
    int s0 = eidx[p], s1 = eidx[p + 1], s2 = eidx[p + 2], s3 = eidx[p + 3];
    const float4* h0 = h4 + (long long)s0 * ROW;
    const float4* h1 = h4 + (long long)s1 * ROW;
    const float4* h2 = h4 + (long long)s2 * ROW;
    const float4* h3 = h4 + (long long)s3 * ROW;
#pragma unroll
    for (int j = 0; j < ROWF4; ++j) {
      float4 a = h0[j * 64 + lane];
      float4 b = h1[j * 64 + lane];
      float4 c = h2[j * 64 + lane];
      float4 d = h3[j * 64 + lane];
      if (HASBN) {
        a = bnrelu4(a, sc[j], sh[j]);
        b = bnrelu4(b, sc[j], sh[j]);
        c = bnrelu4(c, sc[j], sh[j]);
        d = bnrelu4(d, sc[j], sh[j]);
      }
      v[j].x += (a.x + b.x) + (c.x + d.x);
      v[j].y += (a.y + b.y) + (c.y + d.y);
      v[j].z += (a.z + b.z) + (c.z + d.z);
      v[j].w += (a.w + b.w) + (c.w + d.w);
    }
  }
  for (; p < pe; ++p) {
    int s0 = eidx[p];
    const float4* h0 = h4 + (long long)s0 * ROW;
#pragma unroll
    for (int j = 0; j < ROWF4; ++j) {
      float4 a = h0[j * 64 + lane];
      if (HASBN) a = bnrelu4(a, sc[j], sh[j]);
      v[j].x += a.x;
      v[j].y += a.y;
      v[j].z += a.z;
      v[j].w += a.w;
    }
  }
  // packed split write
  const int nd = n & 63, tile = n >> 6;
  const int nf = nd >> 4, ccs = nd & 15;
#pragma unroll
  for (int j = 0; j < ROWF4; ++j) {
    int cj = j * 64 + lane;      // float4 chunk index == k-quad index
    int ks = cj >> 3, k4 = cj & 7;
    size_t base = ((size_t)tile * (ROWF4 * 8) + ks) * 4096 +
                  (size_t)nf * 512 + (size_t)(k4 >> 1) * 128 + (size_t)ccs * 8 +
                  (size_t)(k4 & 1) * 4;
    split4_store(v[j], zp + base, zp + base + 2048);
  }
}

// ------------------------------------------------- W pre-pack: transpose + split + fragment order
__global__ __launch_bounds__(256) void wt_build(const float* __restrict__ W, // [K][512]
                                                unsigned short* __restrict__ Wp,
                                                int KS) {
  int gid = blockIdx.x * 256 + threadIdx.x;
  int total = 2 * KS * 8192;
  if (gid >= total) return;
  int blk = gid >> 13;
  int rem = gid & 8191;
  int cf = rem >> 9;
  int q = (rem >> 7) & 3;
  int c = (rem >> 3) & 15;
  int j = rem & 7;
  int bx = blk / KS, ks = blk - bx * KS;
  int chan = bx * 256 + cf * 16 + c;
  int k = ks * 32 + q * 8 + j;
  float v = W[(size_t)k * 512 + chan];
  unsigned short h, l;
  split_bf16(v, h, l);
  Wp[(size_t)blk * 16384 + rem] = h;
  Wp[(size_t)blk * 16384 + 8192 + rem] = l;
}

// ------------------------------------------------- LDS-free split-bf16 MFMA GEMM on packed A
// C = act(A @ W + bias); A packed fragment-order (hi/lo), W packed (wt_build).
// Grid (2, NT); 256 thr / 4 waves; no LDS, no barriers.
template <int STATS, int PACKOUT>
__global__ __launch_bounds__(256) void gemm_pk(const unsigned short* __restrict__ Ap,
                                               const unsigned short* __restrict__ Wp,
                                               const float* __restrict__ bias,
                                               float* __restrict__ Cf,
                                               unsigned short* __restrict__ Cp,
                                               float* __restrict__ stat_sum,
                                               float* __restrict__ stat_sq,
                                               int N, int KS, int relu) {
  const int tid = threadIdx.x;
  const int wv = tid >> 6, ln = tid & 63;
  const int bx = blockIdx.x;
  const int tile = blockIdx.y;
  const int n0 = tile * 64;

  f32x4 acc[4][4];
#pragma unroll
  for (int i = 0; i < 4; ++i)
#pragma unroll
    for (int j = 0; j < 4; ++j) acc[i][j] = f32x4{0.f, 0.f, 0.f, 0.f};

  const unsigned short* wp =
      Wp + ((size_t)bx * KS) * 16384 + (size_t)(wv * 4) * 512 + (size_t)ln * 8;
  const unsigned short* ap = Ap + (size_t)tile * KS * 4096 + (size_t)ln * 8;

  for (int ks = 0; ks < KS; ++ks) {
    const unsigned short* w = wp + (size_t)ks * 16384;
    const unsigned short* a = ap + (size_t)ks * 4096;
    bf16x8 wh[4], wl[4], ah[4], al[4];
#pragma unroll
    for (int i = 0; i < 4; ++i) {
      wh[i] = *(const bf16x8*)(w + i * 512);
      wl[i] = *(const bf16x8*)(w + 8192 + i * 512);
    }
#pragma unroll
    for (int j = 0; j < 4; ++j) {
      ah[j] = *(const bf16x8*)(a + j * 512);
      al[j] = *(const bf16x8*)(a + 2048 + j * 512);
    }
#pragma unroll
    for (int i = 0; i < 4; ++i)
#pragma unroll
      for (int j = 0; j < 4; ++j) {
        acc[i][j] = __builtin_amdgcn_mfma_f32_16x16x32_bf16(wh[i], ah[j], acc[i][j], 0, 0, 0);
        acc[i][j] = __builtin_amdgcn_mfma_f32_16x16x32_bf16(wh[i], al[j], acc[i][j], 0, 0, 0);
        acc[i][j] = __builtin_amdgcn_mfma_f32_16x16x32_bf16(wl[i], ah[j], acc[i][j], 0, 0, 0);
      }
  }

  // epilogue: D row = chan ((ln>>4)*4+reg within frag), col = node (ln&15)
  const int chanb = bx * 256 + wv * 64 + (ln >> 4) * 4;
  float4 s4[4], q4[4];
  if (STATS) {
#pragma unroll
    for (int i = 0; i < 4; ++i) {
      s4[i] = make_float4(0.f, 0.f, 0.f, 0.f);
      q4[i] = make_float4(0.f, 0.f, 0.f, 0.f);
    }
  }
#pragma unroll
  for (int j = 0; j < 4; ++j) {
    int node = n0 + j * 16 + (ln & 15);
    bool valid = node < N;
    int nd = node & 63;
    int tile2 = node >> 6, nf = nd >> 4, ccs = nd & 15;
#pragma unroll
    for (int i = 0; i < 4; ++i) {
      int chan = chanb + i * 16;
      float4 bv = *(const float4*)(bias + chan);
      f32x4 a = acc[i][j];
      float4 o;
      o.x = a[0] + bv.x;
      o.y = a[1] + bv.y;
      o.z = a[2] + bv.z;
      o.w = a[3] + bv.w;
      if (relu) {
        o.x = fmaxf(o.x, 0.f);
        o.y = fmaxf(o.y, 0.f);
        o.z = fmaxf(o.z, 0.f);
        o.w = fmaxf(o.w, 0.f);
      }
      if (PACKOUT) {
        if (valid) {
          size_t base = ((size_t)tile2 * 16 + (size_t)(chan >> 5)) * 4096 +
                        (size_t)nf * 512 + (size_t)((chan >> 3) & 3) * 128 +
                        (size_t)ccs * 8 + (size_t)((chan >> 2) & 1) * 4;
          split4_store(o, Cp + base, Cp + base + 2048);
        }
      } else {
        if (valid) *(float4*)(Cf + (size_t)node * 512 + chan) = o;
        if (STATS) {
          if (!valid) o = make_float4(0.f, 0.f, 0.f, 0.f);
          s4[i].x += o.x; s4[i].y += o.y; s4[i].z += o.z; s4[i].w += o.w;
          q4[i].x += o.x * o.x; q4[i].y += o.y * o.y;
          q4[i].z += o.z * o.z; q4[i].w += o.w * o.w;
        }
      }
    }
  }
  if (STATS) {
#pragma unroll
    for (int i = 0; i < 4; ++i) {
#pragma unroll
      for (int mask = 1; mask < 16; mask <<= 1) {
        s4[i].x += __shfl_xor(s4[i].x, mask);
        s4[i].y += __shfl_xor(s4[i].y, mask);
        s4[i].z += __shfl_xor(s4[i].z, mask);
        s4[i].w += __shfl_xor(s4[i].w, mask);
        q4[i].x += __shfl_xor(q4[i].x, mask);
        q4[i].y += __shfl_xor(q4[i].y, mask);
        q4[i].z += __shfl_xor(q4[i].z, mask);
        q4[i].w += __shfl_xor(q4[i].w, mask);
      }
    }
    if ((ln & 15) == 0) {
#pragma unroll
      for (int i = 0; i < 4; ++i) {
        int chan = chanb + i * 16;
        atomicAdd(&stat_sum[chan + 0], s4[i].x);
        atomicAdd(&stat_sum[chan + 1], s4[i].y);
        atomicAdd(&stat_sum[chan + 2], s4[i].z);
        atomicAdd(&stat_sum[chan + 3], s4[i].w);
        atomicAdd(&stat_sq[chan + 0], q4[i].x);
        atomicAdd(&stat_sq[chan + 1], q4[i].y);
        atomicAdd(&stat_sq[chan + 2], q4[i].z);
        atomicAdd(&stat_sq[chan + 3], q4[i].w);
      }
    }
  }
}

// ------------------------------------------------- BN finalize: (sum,sumsq,g,b) -> (scale,shift)
__global__ __launch_bounds__(512) void bn_finalize(const float* __restrict__ sum,
                                                   const float* __restrict__ sumsq,
                                                   const float* __restrict__ g,
                                                   const float* __restrict__ b,
                                                   float* __restrict__ scale,
                                                   float* __restrict__ shift) {
  const int c = threadIdx.x;
  const float invN = 1.0f / (float)N_NODES;
  float mu = sum[c] * invN;
  float var = sumsq[c] * invN - mu * mu;
  float sc = rsqrtf(var + BN_EPS) * g[c];
  scale[c] = sc;
  shift[c] = fmaf(-mu, sc, b[c]);
}

// ------------------------------------------------- pool bounds: start[g] = lower_bound(batch, g)
__global__ __launch_bounds__(512) void pool_bounds(const int* __restrict__ batch,
                                                   int* __restrict__ gstart) {
  const int g = threadIdx.x;
  int lo = 0, hi = N_NODES;
  while (lo < hi) {
    int mid = (lo + hi) >> 1;
    if (batch[mid] < g) lo = mid + 1;
    else hi = mid;
  }
  gstart[g] = lo;
  if (g == 0) gstart[N_GRAPHS] = N_NODES;
}

// ------------------------------------------------- segmented add pool + fused BN -> packed output
__global__ __launch_bounds__(128) void gpool_bn(const float4* __restrict__ z4,
                                                const int* __restrict__ gstart,
                                                const float4* __restrict__ scale4,
                                                const float4* __restrict__ shift4,
                                                unsigned short* __restrict__ gpp) {
  const int g = blockIdx.x;
  const int t = threadIdx.x;  // 0..127 -> float4 chunk
  const int s = gstart[g], e = gstart[g + 1];
  const float4 sc = scale4[t], sh = shift4[t];
  float4 acc = make_float4(0.f, 0.f, 0.f, 0.f);
  for (int n = s; n < e; ++n) {
    float4 v = bnrelu4(z4[(size_t)n * 128 + t], sc, sh);
    acc.x += v.x;
    acc.y += v.y;
    acc.z += v.z;
    acc.w += v.w;
  }
  const int tile = g >> 6, nd = g & 63;
  const int nf = nd >> 4, ccs = nd & 15;
  const int ks = t >> 3, k4 = t & 7;
  size_t base = ((size_t)tile * 16 + ks) * 4096 + (size_t)nf * 512 +
                (size_t)(k4 >> 1) * 128 + (size_t)ccs * 8 + (size_t)(k4 & 1) * 4;
  split4_store(acc, gpp + base, gpp + base + 2048);
}

// ------------------------------------------------- classifier tail
__global__ __launch_bounds__(64) void clf2_softmax(const float* __restrict__ hidden,
                                                   const float* __restrict__ w2,
                                                   const float* __restrict__ b2,
                                                   float* __restrict__ out) {
  const int g = blockIdx.x;
  const int lane = threadIdx.x;
  float acc[10];
#pragma unroll
  for (int j = 0; j < 10; ++j) acc[j] = 0.f;
  for (int k = lane; k < HID; k += 64) {
    float hv = hidden[(long long)g * HID + k];
#pragma unroll
    for (int j = 0; j < 10; ++j) acc[j] += hv * w2[k * 10 + j];
  }
#pragma unroll
  for (int j = 0; j < 10; ++j) {
    for (int o = 32; o > 0; o >>= 1) acc[j] += __shfl_down(acc[j], o);
  }
  if (lane == 0) {
    float lg[10], pb[10];
    float mx = -1e30f;
#pragma unroll
    for (int j = 0; j < 10; ++j) {
      lg[j] = acc[j] + b2[j];
      mx = fmaxf(mx, lg[j]);
    }
    float se = 0.f;
#pragma unroll
    for (int j = 0; j < 10; ++j) {
      pb[j] = __expf(lg[j] - mx);
      se += pb[j];
    }
    float inv = 1.f / se;
    int am = 0;
    float best = lg[0];
#pragma unroll
    for (int j = 1; j < 10; ++j) {
      if (lg[j] > best) { best = lg[j]; am = j; }
    }
#pragma unroll
    for (int j = 0; j < 10; ++j) out[g * 10 + j] = lg[j];
#pragma unroll
    for (int j = 0; j < 10; ++j) out[N_GRAPHS * 10 + g * 10 + j] = pb[j] * inv;
    out[2 * N_GRAPHS * 10 + g] = (float)am;
#pragma unroll
    for (int j = 0; j < 10; ++j)
      out[2 * N_GRAPHS * 10 + N_GRAPHS + g * 10 + j] = (j == am) ? 1.f : 0.f;
  }
}

// ----------------------------------------------------------------- launch
extern "C" void kernel_launch(void* const* d_in, const int* in_sizes, int n_in,
                              void* d_out, int out_size, void* d_ws, size_t ws_size,
                              hipStream_t stream) {
  const float* x = (const float*)d_in[0];
  const int* src = (const int*)d_in[1];
  const int* dstE = src + N_EDGES;
  const int* batch = (const int*)d_in[2];
  const float* w0a = (const float*)d_in[3];
  const float* b0a = (const float*)d_in[4];
  const float* w0b = (const float*)d_in[5];
  const float* b0b = (const float*)d_in[6];
  const float* w1a = (const float*)d_in[7];
  const float* b1a = (const float*)d_in[8];
  const float* w1b = (const float*)d_in[9];
  const float* b1b = (const float*)d_in[10];
  const float* w2a = (const float*)d_in[11];
  const float* b2a = (const float*)d_in[12];
  const float* w2b = (const float*)d_in[13];
  const float* b2b = (const float*)d_in[14];
  const float* bng[3] = {(const float*)d_in[15], (const float*)d_in[17], (const float*)d_in[19]};
  const float* bnb[3] = {(const float*)d_in[16], (const float*)d_in[18], (const float*)d_in[20]};
  const float* clf_w1 = (const float*)d_in[21];
  const float* clf_b1 = (const float*)d_in[22];
  const float* clf_w2 = (const float*)d_in[23];
  const float* clf_b2 = (const float*)d_in[24];
  float* out = (float*)d_out;

  // ---- workspace layout (~218 MB); buffers sized for max(float gen, packed gen)
  const size_t BUF = 25624576;  // floats; = 782*16*4096 ushorts for packed KS=16
  float* bufA = (float*)d_ws;
  float* bufB = bufA + BUF;
  float* bnsum = bufB + BUF;          // 512
  float* bnsq = bnsum + 512;          // 512
  float* scale = bnsq + 512;          // 512
  float* shift = scale + 512;         // 512
  unsigned short* gpPack = (unsigned short*)(shift + 512);  // 8*16*4096 = 524288 ushorts
  float* hidden = (float*)(gpPack + 524288);                // 262144 floats
  unsigned short* wp0a = (unsigned short*)(hidden + 262144);
  unsigned short* wp0b = wp0a + 262144;
  unsigned short* wp1a = wp0b + 524288;
  unsigned short* wp1b = wp1a + 524288;
  unsigned short* wp2a = wp1b + 524288;
  unsigned short* wp2b = wp2a + 524288;
  unsigned short* wpc1 = wp2b + 524288;
  int* deg = (int*)(wpc1 + 524288);
  int* off = deg + N_NODES;
  int* cursor = off + N_NODES + 1;
  int* eidx = cursor + N_NODES;
  int* gstart = eidx + N_EDGES;  // 513

  // ---- build CSR (dst -> list of src) + pool bounds
  hipMemsetAsync(deg, 0, N_NODES * sizeof(int), stream);
  hipLaunchKernelGGL(hist_dst, dim3(3125), dim3(256), 0, stream, dstE, deg);
  hipLaunchKernelGGL(scan_deg, dim3(1), dim3(1024), 0, stream, deg, off, cursor);
  hipLaunchKernelGGL(fill_csr, dim3(3125), dim3(256), 0, stream, src, dstE, cursor, eidx);
  hipLaunchKernelGGL(pool_bounds, dim3(1), dim3(512), 0, stream, batch, gstart);

  // ---- pre-pack all weights
  hipLaunchKernelGGL(wt_build, dim3(512), dim3(256), 0, stream, w0a, wp0a, 8);
  hipLaunchKernelGGL(wt_build, dim3(1024), dim3(256), 0, stream, w0b, wp0b, 16);
  hipLaunchKernelGGL(wt_build, dim3(1024), dim3(256), 0, stream, w1a, wp1a, 16);
  hipLaunchKernelGGL(wt_build, dim3(1024), dim3(256), 0, stream, w1b, wp1b, 16);
  hipLaunchKernelGGL(wt_build, dim3(1024), dim3(256), 0, stream, w2a, wp2a, 16);
  hipLaunchKernelGGL(wt_build, dim3(1024), dim3(256), 0, stream, w2b, wp2b, 16);
  hipLaunchKernelGGL(wt_build, dim3(1024), dim3(256), 0, stream, clf_w1, wpc1, 16);

  const unsigned short* wpa[3] = {wp0a, wp1a, wp2a};
  const unsigned short* wpb[3] = {wp0b, wp1b, wp2b};
  const float* ba[3] = {b0a, b1a, b2a};
  const float* bb[3] = {b0b, b1b, b2b};

  const int NT = (N_NODES + 63) / 64;   // 782
  const int nagg = (N_NODES + 3) / 4;

  // Ping-pong: each step reads one buffer, writes the other (linear chain).
  float* P = bufA;  // current step input
  float* Q = bufB;  // current step output
  for (int layer = 0; layer < 3; ++layer) {
    // z(pack) = aggregate
    if (layer == 0) {
      hipLaunchKernelGGL((agg_pk<1, 0>), dim3(nagg), dim3(256), 0, stream,
                         (const float4*)x, off, eidx, nullptr, nullptr,
                         (unsigned short*)Q);
    } else {
      hipLaunchKernelGGL((agg_pk<2, 1>), dim3(nagg), dim3(256), 0, stream,
                         (const float4*)P, off, eidx, (const float4*)scale,
                         (const float4*)shift, (unsigned short*)Q);
    }
    { float* t = P; P = Q; Q = t; }  // z pack in P
    // z1(pack) = relu(z @ wa + ba)
    hipLaunchKernelGGL((gemm_pk<0, 1>), dim3(2, NT), dim3(256), 0, stream,
                       (const unsigned short*)P, wpa[layer], ba[layer],
                       (float*)nullptr, (unsigned short*)Q, nullptr, nullptr,
                       N_NODES, (layer == 0) ? 8 : 16, 1);
    { float* t = P; P = Q; Q = t; }  // z1 pack in P
    // z2(float) = z1 @ wb + bb  (+BN stats)
    hipMemsetAsync(bnsum, 0, 2 * 512 * sizeof(float), stream);
    hipLaunchKernelGGL((gemm_pk<1, 0>), dim3(2, NT), dim3(256), 0, stream,
                       (const unsigned short*)P, wpb[layer], bb[layer],
                       Q, (unsigned short*)nullptr, bnsum, bnsq,
                       N_NODES, 16, 0);
    { float* t = P; P = Q; Q = t; }  // z2 float in P
    hipLaunchKernelGGL(bn_finalize, dim3(1), dim3(512), 0, stream,
                       bnsum, bnsq, bng[layer], bnb[layer], scale, shift);
  }

  // global add pool with fused BN+relu -> packed gp
  hipLaunchKernelGGL(gpool_bn, dim3(N_GRAPHS), dim3(128), 0, stream,
                     (const float4*)P, gstart, (const float4*)scale,
                     (const float4*)shift, gpPack);
  // classifier layer 1 (N=512 rows, float out)
  hipLaunchKernelGGL((gemm_pk<0, 0>), dim3(2, 8), dim3(256), 0, stream,
                     (const unsigned short*)gpPack, wpc1, clf_b1,
                     hidden, (unsigned short*)nullptr, nullptr, nullptr,
                     N_GRAPHS, 16, 1);
  // classifier layer 2 + softmax + argmax + one_hot
  hipLaunchKernelGGL(clf2_softmax, dim3(N_GRAPHS), dim3(64), 0, stream,
                     hidden, clf_w2, clf_b2, out);
}